// Round 11
// baseline (339.103 us; speedup 1.0000x reference)
//
#include <hip/hip_runtime.h>
#include <stdint.h>

// K-Planes hash-grid encoder, MI355X.  Round 11.
// Model (r1-r10): divergent vector-memory requests (incl. scattered stores)
// cost ~4.3-4.8us/M, ADDITIVE system-wide; VALU/LDS work hides under them.
// => minimize total request count.
//  memset: zero hist/cursor
//  K0 packhist: pts -> pts4 (float4) + 3-plane 16x16 bucket histograms
//  K1 scatter: 3-plane counting sort -> sort16 (c0,c1,orig)
//  K2 mega, 3 regions (sm 29.6KB -> 5 blk/CU, 20 waves):
//    [0,768)    low:  l6-11 per (plane,bucket), 3670-entry LDS rect union,
//               interp 6 lvls, 3 scattered float4/pt -> ws2[orig][18] (4.7M)
//    [768,1152) lds05: l0-5 full-table LDS sets {l0-3,l4,l5a,l5b}x3planes,
//               natural pt order -> ws05[(plane*6+l)][pt] COALESCED (0 scatter)
//    [1152,9344) hi: l12-15, 3 planes merged per block (xcd b&7 -> 1 lvl/XCD),
//               paired float4 gathers (18.9M), in-kernel 3-plane product ->
//               wsP[lvl-12][pt] coalesced
//  K3 comb: join ws05-product + ws2-product + wsP copy -> out
// Fallbacks: Plan B (r2 3-pass + transpose), mono.

#define NPTS   524288u
#define TSIZE  524288u
#define TMASK  0x7FFFFu
#define PRIME1 2654435761u

__constant__ float c_res[16] = {
    16.f, 22.f, 30.f, 42.f, 58.f, 80.f, 111.f, 153.f,
    212.f, 294.f, 406.f, 561.f, 775.f, 1072.f, 1481.f, 2047.f
};
__constant__ int      c_resi6[6] = {111, 153, 212, 294, 406, 561};  // l6-11
__constant__ uint32_t c_R03[4]   = {17, 23, 31, 43};
__constant__ uint32_t c_off03[4] = {0, 289, 818, 1779};             // sum 3628

// ---------------- K0: pack pts4 + 3-plane bucket histograms -----------------
__global__ __launch_bounds__(256) void k_packhist(
    const float* __restrict__ pts, float4* __restrict__ pts4,
    uint32_t* __restrict__ hist)
{
    __shared__ uint32_t lh[768];
    const uint32_t b = blockIdx.x, t = threadIdx.x;
    lh[t] = 0u; lh[t + 256u] = 0u; lh[t + 512u] = 0u;
    __syncthreads();
    const uint32_t pt = b * 256u + t;
    const float x = pts[pt * 3u + 0u];
    const float y = pts[pt * 3u + 1u];
    const float z = pts[pt * 3u + 2u];
    pts4[pt] = make_float4(x, y, z, 0.f);
    const uint32_t bx = min(15u, (uint32_t)(x * 16.f));
    const uint32_t by = min(15u, (uint32_t)(y * 16.f));
    const uint32_t bz = min(15u, (uint32_t)(z * 16.f));
    atomicAdd(&lh[         bx * 16u + by], 1u);
    atomicAdd(&lh[256u +   bx * 16u + bz], 1u);
    atomicAdd(&lh[512u +   by * 16u + bz], 1u);
    __syncthreads();
    if (lh[t])        atomicAdd(&hist[t],        lh[t]);
    if (lh[t + 256u]) atomicAdd(&hist[t + 256u], lh[t + 256u]);
    if (lh[t + 512u]) atomicAdd(&hist[t + 512u], lh[t + 512u]);
}

// ---------------- K1: 3-plane counting-sort scatter --------------------------
__global__ __launch_bounds__(256) void k_scatter(
    const float4* __restrict__ pts4, const uint32_t* __restrict__ hist,
    uint32_t* __restrict__ cursor, float4* __restrict__ sort16)
{
    __shared__ uint32_t su[256], lcnt[256], gb[256], lc2[256];
    const uint32_t b = blockIdx.x, t = threadIdx.x;
    const uint32_t plane = b >> 6, chunk = b & 63u;
    const uint32_t h = hist[plane * 256u + t];
    su[t] = h; lcnt[t] = 0u; lc2[t] = 0u;
    __syncthreads();
    for (uint32_t off = 1u; off < 256u; off <<= 1) {
        uint32_t v = 0u;
        if (t >= off) v = su[t - off];
        __syncthreads();
        su[t] += v;
        __syncthreads();
    }
    const uint32_t mybase = su[t] - h;
    const uint32_t pt0 = chunk * 8192u + t;
    for (uint32_t k = 0; k < 32u; ++k) {
        const float4 c = pts4[pt0 + k * 256u];
        const float c0 = (plane == 2u) ? c.y : c.x;
        const float c1 = (plane == 0u) ? c.y : c.z;
        const uint32_t bb = min(15u, (uint32_t)(c0 * 16.f)) * 16u
                          + min(15u, (uint32_t)(c1 * 16.f));
        atomicAdd(&lcnt[bb], 1u);
    }
    __syncthreads();
    gb[t] = mybase + atomicAdd(&cursor[plane * 256u + t], lcnt[t]);
    __syncthreads();
    float4* __restrict__ sp = sort16 + (size_t)plane * NPTS;
    for (uint32_t k = 0; k < 32u; ++k) {
        const uint32_t pt = pt0 + k * 256u;
        const float4 c = pts4[pt];
        const float c0 = (plane == 2u) ? c.y : c.x;
        const float c1 = (plane == 0u) ? c.y : c.z;
        const uint32_t bb = min(15u, (uint32_t)(c0 * 16.f)) * 16u
                          + min(15u, (uint32_t)(c1 * 16.f));
        const uint32_t r = atomicAdd(&lc2[bb], 1u);
        sp[gb[bb] + r] = make_float4(c0, c1, __uint_as_float(pt), 0.f);
    }
}

// ---------------- K2: MEGA — low(l6-11) | lds05(l0-5) | hi(l12-15) ----------
__global__ __launch_bounds__(256) void k_mega(
    const float4* __restrict__ pts4, const float4* __restrict__ sort16,
    const uint32_t* __restrict__ hist, const float2* __restrict__ tab,
    float2* __restrict__ ws05,    // (18, NPTS) coalesced
    float2* __restrict__ ws2,     // (NPTS, 18) scattered by orig
    float2* __restrict__ wsP)     // (4, NPTS) coalesced, 3-plane products
{
    __shared__ float2 sm[3700];              // 29.6 KB -> 5 blocks/CU
    __shared__ uint32_t Poff[6], Pu0[6], Pu1[6], Pcols[6], Prows[6];
    const uint32_t b = blockIdx.x, t = threadIdx.x;

    if (b < 768u) {
        // ======== low: levels 6-11 for one (plane, 16x16 bucket) ========
        const uint32_t plane  = b >> 8;
        const uint32_t bucket = b & 255u;
        const uint32_t bx = bucket >> 4, by = bucket & 15u;

        uint32_t* su = (uint32_t*)sm;        // scan ws aliases staging buf
        const uint32_t h = hist[plane * 256u + t];
        su[t] = h;
        __syncthreads();
        for (uint32_t off = 1u; off < 256u; off <<= 1) {
            uint32_t v = 0u;
            if (t >= off) v = su[t - off];
            __syncthreads();
            su[t] += v;
            __syncthreads();
        }
        const uint32_t cntB  = hist[plane * 256u + bucket];
        const uint32_t start = su[bucket] - cntB;
        __syncthreads();

        if (t == 0u) {
            uint32_t off = 0u;
            for (uint32_t l = 0; l < 6u; ++l) {
                const int R = c_resi6[l];
                const int u0s = max(0, (int)((bx * (uint32_t)R) >> 4) - 1);
                const int u0e = min(R, (int)(((bx + 1u) * (uint32_t)R) >> 4) + 2);
                const int u1s = max(0, (int)((by * (uint32_t)R) >> 4) - 1);
                const int u1e = min(R, (int)(((by + 1u) * (uint32_t)R) >> 4) + 2);
                const uint32_t rows = (uint32_t)(u0e - u0s + 1);
                const uint32_t cols = (uint32_t)(u1e - u1s + 1);
                Poff[l] = off; Pu0[l] = (uint32_t)u0s; Pu1[l] = (uint32_t)u1s;
                Pcols[l] = cols; Prows[l] = rows;
                off += rows * cols;
            }
        }
        __syncthreads();

        for (uint32_t l = 0; l < 6u; ++l) {  // divergent hash staging (2.6M)
            const uint32_t off = Poff[l], u0s = Pu0[l], u1s = Pu1[l];
            const uint32_t cols = Pcols[l];
            const uint32_t E = Prows[l] * cols;
            const uint32_t tb = (plane * 16u + 6u + l) * TSIZE;
            for (uint32_t i = t; i < E; i += 256u) {
                const uint32_t r  = i / cols;
                const uint32_t cx = u0s + r;
                const uint32_t cy = u1s + (i - r * cols);
                sm[off + i] = tab[tb + ((cx ^ (cy * PRIME1)) & TMASK)];
            }
        }
        __syncthreads();

        const float4* __restrict__ sp = sort16 + (size_t)plane * NPTS;
        float4* __restrict__ w4 = (float4*)ws2;
        for (uint32_t i = t; i < cntB; i += 256u) {
            const float4 f = sp[start + i];
            const float c0 = f.x, c1 = f.y;
            const uint32_t orig = __float_as_uint(f.z);
            float2 acc[6];
#pragma unroll
            for (int l = 0; l < 6; ++l) {
                const float res = c_res[6 + l];
                const float s0 = c0 * res;
                const float s1 = c1 * res;
                const float f0 = floorf(s0);
                const float f1 = floorf(s1);
                const float r0 = s0 - f0;    // exact f32 match to reference
                const float r1 = s1 - f1;
                const uint32_t u0 = (uint32_t)f0, u1 = (uint32_t)f1;
                const uint32_t cols = Pcols[l];
                const uint32_t ci = Poff[l] + (u0 - Pu0[l]) * cols + (u1 - Pu1[l]);
                const float2 q00 = sm[ci];
                const float2 q01 = sm[ci + 1u];
                const float2 q10 = sm[ci + cols];
                const float2 q11 = sm[ci + cols + 1u];
                const float w00 = (1.f - r0) * (1.f - r1);
                const float w01 = (1.f - r0) * r1;
                const float w10 = r0 * (1.f - r1);
                const float w11 = r0 * r1;
                acc[l] = make_float2(
                    w00 * q00.x + w01 * q01.x + w10 * q10.x + w11 * q11.x,
                    w00 * q00.y + w01 * q01.y + w10 * q10.y + w11 * q11.y);
            }
            const size_t d = (size_t)orig * 9u + (size_t)plane * 3u;
            w4[d + 0] = make_float4(acc[0].x, acc[0].y, acc[1].x, acc[1].y);
            w4[d + 1] = make_float4(acc[2].x, acc[2].y, acc[3].x, acc[3].y);
            w4[d + 2] = make_float4(acc[4].x, acc[4].y, acc[5].x, acc[5].y);
        }
        return;
    }

    if (b < 1152u) {
        // ======== lds05: levels 0-5 full-table LDS, natural order ========
        const uint32_t bb    = b - 768u;
        const uint32_t set   = bb >> 5;      // 0..11
        const uint32_t chunk = bb & 31u;
        const uint32_t plane = set >> 2;
        const uint32_t kind  = set & 3u;
        const uint32_t pt0   = chunk * 16384u + t;

        if (kind == 0u) {                    // levels 0-3 packed (3628)
#pragma unroll
            for (int l = 0; l < 4; ++l) {
                const uint32_t R = c_R03[l], off = c_off03[l], E = R * R;
                const uint32_t tb = (plane * 16u + (uint32_t)l) * TSIZE;
                for (uint32_t i = t; i < E; i += 256u) {
                    const uint32_t cx = i / R, cy = i - cx * R;
                    sm[off + i] = tab[tb + ((cx ^ (cy * PRIME1)) & TMASK)];
                }
            }
            __syncthreads();
            for (uint32_t k = 0; k < 64u; ++k) {
                const uint32_t pt = pt0 + k * 256u;
                const float4 c4 = pts4[pt];
                const float c0 = (plane == 2u) ? c4.y : c4.x;
                const float c1 = (plane == 0u) ? c4.y : c4.z;
#pragma unroll
                for (int l = 0; l < 4; ++l) {
                    const uint32_t R = c_R03[l], off = c_off03[l];
                    const float res = c_res[l];
                    const float s0 = c0 * res;
                    const float s1 = c1 * res;
                    const float f0 = floorf(s0);
                    const float f1 = floorf(s1);
                    const float r0 = s0 - f0;
                    const float r1 = s1 - f1;
                    const uint32_t ci = off + (uint32_t)f0 * R + (uint32_t)f1;
                    const float2 q00 = sm[ci];
                    const float2 q01 = sm[ci + 1u];
                    const float2 q10 = sm[ci + R];
                    const float2 q11 = sm[ci + R + 1u];
                    const float w00 = (1.f - r0) * (1.f - r1);
                    const float w01 = (1.f - r0) * r1;
                    const float w10 = r0 * (1.f - r1);
                    const float w11 = r0 * r1;
                    ws05[(size_t)(plane * 6u + (uint32_t)l) * NPTS + pt] =
                        make_float2(
                        w00 * q00.x + w01 * q01.x + w10 * q10.x + w11 * q11.x,
                        w00 * q00.y + w01 * q01.y + w10 * q10.y + w11 * q11.y);
                }
            }
        } else if (kind == 1u) {             // level 4 full (R=59, 3481)
            const uint32_t R = 59u, E = 3481u;
            const uint32_t tb = (plane * 16u + 4u) * TSIZE;
            for (uint32_t i = t; i < E; i += 256u) {
                const uint32_t cx = i / R, cy = i - cx * R;
                sm[i] = tab[tb + ((cx ^ (cy * PRIME1)) & TMASK)];
            }
            __syncthreads();
            for (uint32_t k = 0; k < 64u; ++k) {
                const uint32_t pt = pt0 + k * 256u;
                const float4 c4 = pts4[pt];
                const float c0 = (plane == 2u) ? c4.y : c4.x;
                const float c1 = (plane == 0u) ? c4.y : c4.z;
                const float s0 = c0 * 58.f;
                const float s1 = c1 * 58.f;
                const float f0 = floorf(s0);
                const float f1 = floorf(s1);
                const float r0 = s0 - f0;
                const float r1 = s1 - f1;
                const uint32_t ci = (uint32_t)f0 * R + (uint32_t)f1;
                const float2 q00 = sm[ci];
                const float2 q01 = sm[ci + 1u];
                const float2 q10 = sm[ci + R];
                const float2 q11 = sm[ci + R + 1u];
                const float w00 = (1.f - r0) * (1.f - r1);
                const float w01 = (1.f - r0) * r1;
                const float w10 = r0 * (1.f - r1);
                const float w11 = r0 * r1;
                ws05[(size_t)(plane * 6u + 4u) * NPTS + pt] = make_float2(
                    w00 * q00.x + w01 * q01.x + w10 * q10.x + w11 * q11.x,
                    w00 * q00.y + w01 * q01.y + w10 * q10.y + w11 * q11.y);
            }
        } else {                             // level 5 stripes (R=81)
            const uint32_t lo  = (kind == 2u) ? 0u : 40u;
            const uint32_t hiX = lo + 40u;   // u0 in [lo, lo+40)
            const uint32_t R = 81u, E = 41u * 81u;
            const uint32_t tb = (plane * 16u + 5u) * TSIZE;
            for (uint32_t i = t; i < E; i += 256u) {
                const uint32_t r = i / R;
                const uint32_t cx = lo + r, cy = i - r * R;
                sm[i] = tab[tb + ((cx ^ (cy * PRIME1)) & TMASK)];
            }
            __syncthreads();
            for (uint32_t k = 0; k < 64u; ++k) {
                const uint32_t pt = pt0 + k * 256u;
                const float4 c4 = pts4[pt];
                const float c0 = (plane == 2u) ? c4.y : c4.x;
                const float c1 = (plane == 0u) ? c4.y : c4.z;
                const float s0 = c0 * 80.f;
                const float s1 = c1 * 80.f;
                const float f0 = floorf(s0);
                const float f1 = floorf(s1);
                const uint32_t u0 = (uint32_t)f0;
                if (u0 >= lo && u0 < hiX) {
                    const float r0 = s0 - f0;
                    const float r1 = s1 - f1;
                    const uint32_t ci = (u0 - lo) * R + (uint32_t)f1;
                    const float2 q00 = sm[ci];
                    const float2 q01 = sm[ci + 1u];
                    const float2 q10 = sm[ci + R];
                    const float2 q11 = sm[ci + R + 1u];
                    const float w00 = (1.f - r0) * (1.f - r1);
                    const float w01 = (1.f - r0) * r1;
                    const float w10 = r0 * (1.f - r1);
                    const float w11 = r0 * r1;
                    ws05[(size_t)(plane * 6u + 5u) * NPTS + pt] = make_float2(
                        w00 * q00.x + w01 * q01.x + w10 * q10.x + w11 * q11.x,
                        w00 * q00.y + w01 * q01.y + w10 * q10.y + w11 * q11.y);
                }
            }
        }
        return;
    }

    // ======== hi: levels 12-15, 3 planes merged, in-kernel product ========
    const uint32_t hb  = b - 1152u;          // 1152%8==0: b&7 mapping kept
    const uint32_t xcd = hb & 7u;
    const uint32_t s   = hb >> 3;            // 0..1023
    const uint32_t lvl = 12u + (xcd >> 1);   // 1 level per XCD pair... 2 XCD/lvl
    const uint32_t chunk = ((xcd & 1u) << 10) + s;
    const uint32_t pt  = chunk * 256u + t;
    const float4 c4 = pts4[pt];
    const float pc0[3] = {c4.x, c4.x, c4.y};
    const float pc1[3] = {c4.y, c4.z, c4.z};
    const float res = c_res[lvl];
    const float4* __restrict__ tab4 = (const float4*)tab;

    float4 P0[3], P1[3];
    float2 Q0[3], Q1[3];
    float  r0[3], r1[3];
    uint32_t sel0[3], sel1[3], oddm[3];

#pragma unroll
    for (int p = 0; p < 3; ++p) {            // issue all 3 planes' loads
        const uint32_t gabs = (uint32_t)p * 16u + lvl;
        const uint32_t tb = gabs * TSIZE;
        const uint32_t b4 = gabs * (TSIZE / 2u);
        const float s0 = pc0[p] * res;
        const float s1 = pc1[p] * res;
        const float f0 = floorf(s0);
        const float f1 = floorf(s1);
        r0[p] = s0 - f0;                     // exact f32 match to reference
        r1[p] = s1 - f1;
        const uint32_t u0  = (uint32_t)f0;
        const uint32_t hy0 = (uint32_t)f1 * PRIME1;
        const uint32_t hy1 = hy0 + PRIME1;
        const uint32_t i00 = ( u0        ^ hy0) & TMASK;
        const uint32_t i01 = ( u0        ^ hy1) & TMASK;
        const uint32_t i10 = ((u0 + 1u)  ^ hy0) & TMASK;
        const uint32_t i11 = ((u0 + 1u)  ^ hy1) & TMASK;
        sel0[p] = i00 & 1u;
        sel1[p] = i01 & 1u;
        oddm[p] = u0 & 1u;
        P0[p] = tab4[b4 + (i00 >> 1)];       // covers t00 (+t10 if u0 even)
        P1[p] = tab4[b4 + (i01 >> 1)];       // covers t01 (+t11 if u0 even)
        Q0[p] = make_float2(0.f, 0.f);
        Q1[p] = make_float2(0.f, 0.f);
        if (oddm[p]) {                       // exec-masked, ~50% lanes
            Q0[p] = tab[tb + i10];
            Q1[p] = tab[tb + i11];
        }
    }
    float prod0 = 1.f, prod1 = 1.f;
#pragma unroll
    for (int p = 0; p < 3; ++p) {
        const float2 lo0 = make_float2(P0[p].x, P0[p].y);
        const float2 hi0 = make_float2(P0[p].z, P0[p].w);
        const float2 lo1 = make_float2(P1[p].x, P1[p].y);
        const float2 hi1 = make_float2(P1[p].z, P1[p].w);
        const float2 t00 = sel0[p] ? hi0 : lo0;
        const float2 t01 = sel1[p] ? hi1 : lo1;
        const float2 t10 = oddm[p] ? Q0[p] : (sel0[p] ? lo0 : hi0);
        const float2 t11 = oddm[p] ? Q1[p] : (sel1[p] ? lo1 : hi1);
        const float w00 = (1.f - r0[p]) * (1.f - r1[p]);
        const float w01 = (1.f - r0[p]) * r1[p];
        const float w10 = r0[p] * (1.f - r1[p]);
        const float w11 = r0[p] * r1[p];
        prod0 *= w00 * t00.x + w01 * t01.x + w10 * t10.x + w11 * t11.x;
        prod1 *= w00 * t00.y + w01 * t01.y + w10 * t10.y + w11 * t11.y;
    }
    wsP[(size_t)(lvl - 12u) * NPTS + pt] = make_float2(prod0, prod1);
}

// ---------------- K3: combine -> out -----------------------------------------
__global__ __launch_bounds__(256) void k_comb(
    const float2* __restrict__ ws05, const float2* __restrict__ ws2,
    const float2* __restrict__ wsP, float2* __restrict__ out)
{
    __shared__ float2 s05[1152];             // 18 rows x 64 pts
    __shared__ float2 s2[1152];              // 64 pts x 18
    __shared__ float2 spd[256];              // 4 rows x 64 pts
    const uint32_t b = blockIdx.x, t = threadIdx.x;
    const uint32_t pt0 = b * 64u;
    for (uint32_t i = t; i < 1152u; i += 256u) {
        const uint32_t row = i >> 6, p = i & 63u;
        s05[i] = ws05[(size_t)row * NPTS + pt0 + p];
    }
    const float2* __restrict__ w2src = ws2 + (size_t)pt0 * 18u;
    for (uint32_t i = t; i < 1152u; i += 256u) s2[i] = w2src[i];
    {
        const uint32_t row = t >> 6, p = t & 63u;
        spd[t] = wsP[(size_t)row * NPTS + pt0 + p];
    }
    __syncthreads();
#pragma unroll
    for (uint32_t k = 0; k < 4u; ++k) {
        const uint32_t e = t + k * 256u;
        const uint32_t pt = e >> 4, l = e & 15u;
        float2 v;
        if (l < 6u) {
            const float2 a  = s05[l * 64u + pt];
            const float2 bb = s05[(6u + l) * 64u + pt];
            const float2 c  = s05[(12u + l) * 64u + pt];
            v = make_float2(a.x * bb.x * c.x, a.y * bb.y * c.y);
        } else if (l < 12u) {
            const uint32_t j = l - 6u;
            const float2 a  = s2[pt * 18u + j];
            const float2 bb = s2[pt * 18u + 6u + j];
            const float2 c  = s2[pt * 18u + 12u + j];
            v = make_float2(a.x * bb.x * c.x, a.y * bb.y * c.y);
        } else {
            v = spd[(l - 12u) * 64u + pt];
        }
        out[(size_t)(pt0 + pt) * 16u + l] = v;
    }
}

// ---------------- Plan B fallback: r2 3-pass + transpose ---------------------
template <int P, bool FIRST>
__global__ __launch_bounds__(256) void kplane_pass(
    const float* __restrict__ pts, const float2* __restrict__ tab,
    float2* __restrict__ ws)
{
    const uint32_t b     = blockIdx.x;
    const uint32_t xcd   = b & 7u;
    const uint32_t s     = b >> 3;
    const uint32_t gi    = s >> 11;
    const uint32_t chunk = s & 2047u;
    const uint32_t lvl   = gi * 8u + xcd;
    const uint32_t pt    = chunk * 256u + threadIdx.x;
    constexpr int c0 = (P == 2) ? 1 : 0;
    constexpr int c1 = (P == 0) ? 1 : 2;
    const float a0  = pts[pt * 3u + c0];
    const float a1  = pts[pt * 3u + c1];
    const float res = c_res[lvl];
    const float s0 = a0 * res;
    const float s1 = a1 * res;
    const float f0 = floorf(s0);
    const float f1 = floorf(s1);
    const float r0 = s0 - f0;
    const float r1 = s1 - f1;
    const uint32_t u0 = (uint32_t)f0;
    const uint32_t hy0  = (uint32_t)f1 * PRIME1;
    const uint32_t hy1  = hy0 + PRIME1;
    const uint32_t base = ((uint32_t)P * 16u + lvl) * TSIZE;
    const float2 t00 = tab[base + (( u0       ^ hy0) & TMASK)];
    const float2 t01 = tab[base + (( u0       ^ hy1) & TMASK)];
    const float2 t10 = tab[base + (((u0 + 1u) ^ hy0) & TMASK)];
    const float2 t11 = tab[base + (((u0 + 1u) ^ hy1) & TMASK)];
    const float w00 = (1.f - r0) * (1.f - r1);
    const float w01 = (1.f - r0) * r1;
    const float w10 = r0 * (1.f - r1);
    const float w11 = r0 * r1;
    const float e0 = w00 * t00.x + w01 * t01.x + w10 * t10.x + w11 * t11.x;
    const float e1 = w00 * t00.y + w01 * t01.y + w10 * t10.y + w11 * t11.y;
    const uint32_t widx = lvl * NPTS + pt;
    if (FIRST) {
        ws[widx] = make_float2(e0, e1);
    } else {
        const float2 prev = ws[widx];
        ws[widx] = make_float2(prev.x * e0, prev.y * e1);
    }
}

__global__ __launch_bounds__(256) void kplane_transpose(
    const float2* __restrict__ ws, float2* __restrict__ out)
{
    const uint32_t tid = blockIdx.x * 256u + threadIdx.x;
    const uint32_t lvl = tid & 15u;
    const uint32_t pt  = tid >> 4;
    out[tid] = ws[lvl * NPTS + pt];
}

__global__ __launch_bounds__(256) void kplane_mono(
    const float* __restrict__ pts, const float2* __restrict__ tab,
    float2* __restrict__ out)
{
    const uint32_t tid = blockIdx.x * 256u + threadIdx.x;
    const uint32_t pt  = tid >> 4;
    const uint32_t lvl = tid & 15u;
    const float x = pts[pt * 3u + 0u];
    const float y = pts[pt * 3u + 1u];
    const float z = pts[pt * 3u + 2u];
    const float res = c_res[lvl];
    const float a0[3] = {x, x, y};
    const float a1[3] = {y, z, z};
    float p0 = 1.f, p1 = 1.f;
#pragma unroll
    for (int pl = 0; pl < 3; ++pl) {
        const float s0 = a0[pl] * res;
        const float s1 = a1[pl] * res;
        const float f0 = floorf(s0);
        const float f1 = floorf(s1);
        const float r0 = s0 - f0;
        const float r1 = s1 - f1;
        const uint32_t u0 = (uint32_t)f0;
        const uint32_t hy0 = (uint32_t)f1 * PRIME1;
        const uint32_t hy1 = hy0 + PRIME1;
        const uint32_t base = ((uint32_t)pl * 16u + lvl) * TSIZE;
        const float2 t00 = tab[base + (( u0       ^ hy0) & TMASK)];
        const float2 t01 = tab[base + (( u0       ^ hy1) & TMASK)];
        const float2 t10 = tab[base + (((u0 + 1u) ^ hy0) & TMASK)];
        const float2 t11 = tab[base + (((u0 + 1u) ^ hy1) & TMASK)];
        const float w00 = (1.f - r0) * (1.f - r1);
        const float w01 = (1.f - r0) * r1;
        const float w10 = r0 * (1.f - r1);
        const float w11 = r0 * r1;
        p0 *= w00 * t00.x + w01 * t01.x + w10 * t10.x + w11 * t11.x;
        p1 *= w00 * t00.y + w01 * t01.y + w10 * t10.y + w11 * t11.y;
    }
    out[pt * 16u + lvl] = make_float2(p0, p1);
}

extern "C" void kernel_launch(void* const* d_in, const int* in_sizes, int n_in,
                              void* d_out, int out_size, void* d_ws, size_t ws_size,
                              hipStream_t stream) {
    const float*  pts = (const float*)d_in[0];
    const float2* tab = (const float2*)d_in[1];
    float2*       out = (float2*)d_out;

    const size_t wsA = (size_t)40 * NPTS * sizeof(float2);   // 167.8 MB
    const size_t wsB = (size_t)16 * NPTS * sizeof(float2);   //  67.1 MB
    dim3 block256(256u);

    if (ws_size >= wsA) {
        // d_out scratch: pts4 (8.4MB) | sort16 (25.2MB) | hist | cursor
        float4*   pts4   = (float4*)d_out;
        float4*   sort16 = pts4 + NPTS;
        uint32_t* hist   = (uint32_t*)(sort16 + (size_t)3 * NPTS);
        uint32_t* cursor = hist + 768;
        // d_ws: ws05 (18,NPTS) | ws2 (NPTS,18) | wsP (4,NPTS)
        float2* ws05 = (float2*)d_ws;
        float2* ws2  = ws05 + (size_t)18 * NPTS;
        float2* wsP  = ws2  + (size_t)18 * NPTS;

        hipMemsetAsync(hist, 0, 1536u * sizeof(uint32_t), stream);
        hipLaunchKernelGGL(k_packhist, dim3(2048u), block256, 0, stream,
                           pts, pts4, hist);
        hipLaunchKernelGGL(k_scatter,  dim3(192u),  block256, 0, stream,
                           pts4, hist, cursor, sort16);
        hipLaunchKernelGGL(k_mega,     dim3(9344u), block256, 0, stream,
                           pts4, sort16, hist, tab, ws05, ws2, wsP);
        hipLaunchKernelGGL(k_comb,     dim3(NPTS / 64u), block256, 0, stream,
                           ws05, ws2, wsP, out);
    } else if (ws_size >= wsB) {
        float2* ws = (float2*)d_ws;
        dim3 grid(16u * (NPTS / 256u));
        hipLaunchKernelGGL((kplane_pass<0, true >), grid, block256, 0, stream, pts, tab, ws);
        hipLaunchKernelGGL((kplane_pass<1, false>), grid, block256, 0, stream, pts, tab, ws);
        hipLaunchKernelGGL((kplane_pass<2, false>), grid, block256, 0, stream, pts, tab, ws);
        dim3 tgrid((NPTS * 16u) / 256u);
        hipLaunchKernelGGL(kplane_transpose, tgrid, block256, 0, stream, ws, out);
    } else {
        dim3 grid((NPTS * 16u) / 256u);
        hipLaunchKernelGGL(kplane_mono, grid, block256, 0, stream, pts, tab, out);
    }
}

// Round 12
// 313.882 us; speedup vs baseline: 1.0804x; 1.0804x over previous
//
#include <hip/hip_runtime.h>
#include <stdint.h>

// K-Planes hash-grid encoder, MI355X.  Round 12.
// Model (r1-r11): divergent vector-memory requests cost ~4.6us/M ONLY while
// each XCD's gather working set fits its 4MB L2 (r11: 3 tables/XCD -> FETCH
// 501MB, 2x cost). Scattered stores count as requests. Minimize requests AND
// keep one table per XCD phase.
//  memset: zero hist/cursor
//  K0 packhist (r10): pts -> pts2[plane][pt] + per-plane 16x16 histograms
//  K1 scatter  (r10): per-plane counting sort -> sort16 (c0,c1,orig)
//  K2 lowmid: [0,768)  low l6-11 per (plane,bucket): 3670-entry LDS rect
//             union, 4.7M scattered float4 writes -> ws2[orig][18]
//             [768,1152) lds05 l0-5 full-table LDS, natural order ->
//             ws05[(plane*6+l)][pt] coalesced (zero scatter)
//  K3 hi (r9 verbatim): l12-15, 12 groups, one 4MB table per XCD phase
//             (8 full + 4 split), float4 even-u0 pairing, 4 pts/thread
//  K4 comb: join ws05 + ws2 + wsH -> out, coalesced
// Fallbacks: Plan B (r2 3-pass + transpose), mono.

#define NPTS   524288u
#define TSIZE  524288u
#define TMASK  0x7FFFFu
#define PRIME1 2654435761u

__constant__ float c_res[16] = {
    16.f, 22.f, 30.f, 42.f, 58.f, 80.f, 111.f, 153.f,
    212.f, 294.f, 406.f, 561.f, 775.f, 1072.f, 1481.f, 2047.f
};
__constant__ int      c_resi6[6] = {111, 153, 212, 294, 406, 561};  // l6-11
__constant__ uint32_t c_R03[4]   = {17, 23, 31, 43};
__constant__ uint32_t c_off03[4] = {0, 289, 818, 1779};             // sum 3628

// ---------------- K0: pack per-plane coords + bucket histograms -------------
__global__ __launch_bounds__(256) void k_packhist(
    const float* __restrict__ pts, float2* __restrict__ pts2,
    uint32_t* __restrict__ hist)
{
    __shared__ uint32_t lh[768];
    const uint32_t b = blockIdx.x, t = threadIdx.x;
    lh[t] = 0u; lh[t + 256u] = 0u; lh[t + 512u] = 0u;
    __syncthreads();
    const uint32_t pt = b * 256u + t;
    const float x = pts[pt * 3u + 0u];
    const float y = pts[pt * 3u + 1u];
    const float z = pts[pt * 3u + 2u];
    pts2[            pt] = make_float2(x, y);
    pts2[NPTS      + pt] = make_float2(x, z);
    pts2[2u * NPTS + pt] = make_float2(y, z);
    const uint32_t bx = min(15u, (uint32_t)(x * 16.f));
    const uint32_t by = min(15u, (uint32_t)(y * 16.f));
    const uint32_t bz = min(15u, (uint32_t)(z * 16.f));
    atomicAdd(&lh[         bx * 16u + by], 1u);
    atomicAdd(&lh[256u +   bx * 16u + bz], 1u);
    atomicAdd(&lh[512u +   by * 16u + bz], 1u);
    __syncthreads();
    if (lh[t])        atomicAdd(&hist[t],        lh[t]);
    if (lh[t + 256u]) atomicAdd(&hist[t + 256u], lh[t + 256u]);
    if (lh[t + 512u]) atomicAdd(&hist[t + 512u], lh[t + 512u]);
}

// ---------------- K1: counting-sort scatter (local scan) --------------------
__global__ __launch_bounds__(256) void k_scatter(
    const float2* __restrict__ pts2, const uint32_t* __restrict__ hist,
    uint32_t* __restrict__ cursor, float4* __restrict__ sort16)
{
    __shared__ uint32_t su[256], lcnt[256], gb[256], lc2[256];
    const uint32_t b = blockIdx.x, t = threadIdx.x;
    const uint32_t plane = b >> 6, chunk = b & 63u;
    const uint32_t h = hist[plane * 256u + t];
    su[t] = h; lcnt[t] = 0u; lc2[t] = 0u;
    __syncthreads();
    for (uint32_t off = 1u; off < 256u; off <<= 1) {
        uint32_t v = 0u;
        if (t >= off) v = su[t - off];
        __syncthreads();
        su[t] += v;
        __syncthreads();
    }
    const uint32_t mybase = su[t] - h;
    const float2* __restrict__ pp = pts2 + (size_t)plane * NPTS;
    const uint32_t pt0 = chunk * 8192u + t;
    for (uint32_t k = 0; k < 32u; ++k) {
        const float2 c = pp[pt0 + k * 256u];
        const uint32_t bb = min(15u, (uint32_t)(c.x * 16.f)) * 16u
                          + min(15u, (uint32_t)(c.y * 16.f));
        atomicAdd(&lcnt[bb], 1u);
    }
    __syncthreads();
    gb[t] = mybase + atomicAdd(&cursor[plane * 256u + t], lcnt[t]);
    __syncthreads();
    float4* __restrict__ sp = sort16 + (size_t)plane * NPTS;
    for (uint32_t k = 0; k < 32u; ++k) {
        const uint32_t pt = pt0 + k * 256u;
        const float2 c = pp[pt];
        const uint32_t bb = min(15u, (uint32_t)(c.x * 16.f)) * 16u
                          + min(15u, (uint32_t)(c.y * 16.f));
        const uint32_t r = atomicAdd(&lc2[bb], 1u);
        sp[gb[bb] + r] = make_float4(c.x, c.y, __uint_as_float(pt), 0.f);
    }
}

// ---------------- K2: lowmid — low(l6-11 bucketed) | lds05(l0-5) ------------
__global__ __launch_bounds__(256) void k_lowmid(
    const float2* __restrict__ pts2, const float4* __restrict__ sort16,
    const uint32_t* __restrict__ hist, const float2* __restrict__ tab,
    float2* __restrict__ ws05,    // (18, NPTS) coalesced
    float2* __restrict__ ws2)     // (NPTS, 18) scattered by orig
{
    __shared__ float2 sm[3700];              // 29.6 KB -> 5 blocks/CU
    __shared__ uint32_t Poff[6], Pu0[6], Pu1[6], Pcols[6], Prows[6];
    const uint32_t b = blockIdx.x, t = threadIdx.x;

    if (b < 768u) {
        // ======== low: levels 6-11 for one (plane, 16x16 bucket) ========
        const uint32_t plane  = b >> 8;
        const uint32_t bucket = b & 255u;
        const uint32_t bx = bucket >> 4, by = bucket & 15u;

        uint32_t* su = (uint32_t*)sm;        // scan ws aliases staging buf
        const uint32_t h = hist[plane * 256u + t];
        su[t] = h;
        __syncthreads();
        for (uint32_t off = 1u; off < 256u; off <<= 1) {
            uint32_t v = 0u;
            if (t >= off) v = su[t - off];
            __syncthreads();
            su[t] += v;
            __syncthreads();
        }
        const uint32_t cntB  = hist[plane * 256u + bucket];
        const uint32_t start = su[bucket] - cntB;
        __syncthreads();

        if (t == 0u) {
            uint32_t off = 0u;
            for (uint32_t l = 0; l < 6u; ++l) {
                const int R = c_resi6[l];
                const int u0s = max(0, (int)((bx * (uint32_t)R) >> 4) - 1);
                const int u0e = min(R, (int)(((bx + 1u) * (uint32_t)R) >> 4) + 2);
                const int u1s = max(0, (int)((by * (uint32_t)R) >> 4) - 1);
                const int u1e = min(R, (int)(((by + 1u) * (uint32_t)R) >> 4) + 2);
                const uint32_t rows = (uint32_t)(u0e - u0s + 1);
                const uint32_t cols = (uint32_t)(u1e - u1s + 1);
                Poff[l] = off; Pu0[l] = (uint32_t)u0s; Pu1[l] = (uint32_t)u1s;
                Pcols[l] = cols; Prows[l] = rows;
                off += rows * cols;
            }
        }
        __syncthreads();

        for (uint32_t l = 0; l < 6u; ++l) {  // divergent hash staging (2.6M)
            const uint32_t off = Poff[l], u0s = Pu0[l], u1s = Pu1[l];
            const uint32_t cols = Pcols[l];
            const uint32_t E = Prows[l] * cols;
            const uint32_t tb = (plane * 16u + 6u + l) * TSIZE;
            for (uint32_t i = t; i < E; i += 256u) {
                const uint32_t r  = i / cols;
                const uint32_t cx = u0s + r;
                const uint32_t cy = u1s + (i - r * cols);
                sm[off + i] = tab[tb + ((cx ^ (cy * PRIME1)) & TMASK)];
            }
        }
        __syncthreads();

        const float4* __restrict__ sp = sort16 + (size_t)plane * NPTS;
        float4* __restrict__ w4 = (float4*)ws2;
        for (uint32_t i = t; i < cntB; i += 256u) {
            const float4 f = sp[start + i];
            const float c0 = f.x, c1 = f.y;
            const uint32_t orig = __float_as_uint(f.z);
            float2 acc[6];
#pragma unroll
            for (int l = 0; l < 6; ++l) {
                const float res = c_res[6 + l];
                const float s0 = c0 * res;
                const float s1 = c1 * res;
                const float f0 = floorf(s0);
                const float f1 = floorf(s1);
                const float r0 = s0 - f0;    // exact f32 match to reference
                const float r1 = s1 - f1;
                const uint32_t u0 = (uint32_t)f0, u1 = (uint32_t)f1;
                const uint32_t cols = Pcols[l];
                const uint32_t ci = Poff[l] + (u0 - Pu0[l]) * cols + (u1 - Pu1[l]);
                const float2 q00 = sm[ci];
                const float2 q01 = sm[ci + 1u];
                const float2 q10 = sm[ci + cols];
                const float2 q11 = sm[ci + cols + 1u];
                const float w00 = (1.f - r0) * (1.f - r1);
                const float w01 = (1.f - r0) * r1;
                const float w10 = r0 * (1.f - r1);
                const float w11 = r0 * r1;
                acc[l] = make_float2(
                    w00 * q00.x + w01 * q01.x + w10 * q10.x + w11 * q11.x,
                    w00 * q00.y + w01 * q01.y + w10 * q10.y + w11 * q11.y);
            }
            const size_t d = (size_t)orig * 9u + (size_t)plane * 3u;
            w4[d + 0] = make_float4(acc[0].x, acc[0].y, acc[1].x, acc[1].y);
            w4[d + 1] = make_float4(acc[2].x, acc[2].y, acc[3].x, acc[3].y);
            w4[d + 2] = make_float4(acc[4].x, acc[4].y, acc[5].x, acc[5].y);
        }
        return;
    }

    // ======== lds05: levels 0-5 full-table LDS, natural order ========
    const uint32_t bb    = b - 768u;
    const uint32_t set   = bb >> 5;          // 0..11
    const uint32_t chunk = bb & 31u;
    const uint32_t plane = set >> 2;
    const uint32_t kind  = set & 3u;
    const uint32_t pt0   = chunk * 16384u + t;
    const float2* __restrict__ pp = pts2 + (size_t)plane * NPTS;

    if (kind == 0u) {                        // levels 0-3 packed (3628)
#pragma unroll
        for (int l = 0; l < 4; ++l) {
            const uint32_t R = c_R03[l], off = c_off03[l], E = R * R;
            const uint32_t tb = (plane * 16u + (uint32_t)l) * TSIZE;
            for (uint32_t i = t; i < E; i += 256u) {
                const uint32_t cx = i / R, cy = i - cx * R;
                sm[off + i] = tab[tb + ((cx ^ (cy * PRIME1)) & TMASK)];
            }
        }
        __syncthreads();
        for (uint32_t k = 0; k < 64u; ++k) {
            const uint32_t pt = pt0 + k * 256u;
            const float2 c2 = pp[pt];
#pragma unroll
            for (int l = 0; l < 4; ++l) {
                const uint32_t R = c_R03[l], off = c_off03[l];
                const float res = c_res[l];
                const float s0 = c2.x * res;
                const float s1 = c2.y * res;
                const float f0 = floorf(s0);
                const float f1 = floorf(s1);
                const float r0 = s0 - f0;
                const float r1 = s1 - f1;
                const uint32_t ci = off + (uint32_t)f0 * R + (uint32_t)f1;
                const float2 q00 = sm[ci];
                const float2 q01 = sm[ci + 1u];
                const float2 q10 = sm[ci + R];
                const float2 q11 = sm[ci + R + 1u];
                const float w00 = (1.f - r0) * (1.f - r1);
                const float w01 = (1.f - r0) * r1;
                const float w10 = r0 * (1.f - r1);
                const float w11 = r0 * r1;
                ws05[(size_t)(plane * 6u + (uint32_t)l) * NPTS + pt] =
                    make_float2(
                    w00 * q00.x + w01 * q01.x + w10 * q10.x + w11 * q11.x,
                    w00 * q00.y + w01 * q01.y + w10 * q10.y + w11 * q11.y);
            }
        }
    } else if (kind == 1u) {                 // level 4 full (R=59, 3481)
        const uint32_t R = 59u, E = 3481u;
        const uint32_t tb = (plane * 16u + 4u) * TSIZE;
        for (uint32_t i = t; i < E; i += 256u) {
            const uint32_t cx = i / R, cy = i - cx * R;
            sm[i] = tab[tb + ((cx ^ (cy * PRIME1)) & TMASK)];
        }
        __syncthreads();
        for (uint32_t k = 0; k < 64u; ++k) {
            const uint32_t pt = pt0 + k * 256u;
            const float2 c2 = pp[pt];
            const float s0 = c2.x * 58.f;
            const float s1 = c2.y * 58.f;
            const float f0 = floorf(s0);
            const float f1 = floorf(s1);
            const float r0 = s0 - f0;
            const float r1 = s1 - f1;
            const uint32_t ci = (uint32_t)f0 * R + (uint32_t)f1;
            const float2 q00 = sm[ci];
            const float2 q01 = sm[ci + 1u];
            const float2 q10 = sm[ci + R];
            const float2 q11 = sm[ci + R + 1u];
            const float w00 = (1.f - r0) * (1.f - r1);
            const float w01 = (1.f - r0) * r1;
            const float w10 = r0 * (1.f - r1);
            const float w11 = r0 * r1;
            ws05[(size_t)(plane * 6u + 4u) * NPTS + pt] = make_float2(
                w00 * q00.x + w01 * q01.x + w10 * q10.x + w11 * q11.x,
                w00 * q00.y + w01 * q01.y + w10 * q10.y + w11 * q11.y);
        }
    } else {                                 // level 5 stripes (R=81)
        const uint32_t lo  = (kind == 2u) ? 0u : 40u;
        const uint32_t hiX = lo + 40u;
        const uint32_t R = 81u, E = 41u * 81u;
        const uint32_t tb = (plane * 16u + 5u) * TSIZE;
        for (uint32_t i = t; i < E; i += 256u) {
            const uint32_t r = i / R;
            const uint32_t cx = lo + r, cy = i - r * R;
            sm[i] = tab[tb + ((cx ^ (cy * PRIME1)) & TMASK)];
        }
        __syncthreads();
        for (uint32_t k = 0; k < 64u; ++k) {
            const uint32_t pt = pt0 + k * 256u;
            const float2 c2 = pp[pt];
            const float s0 = c2.x * 80.f;
            const float s1 = c2.y * 80.f;
            const float f0 = floorf(s0);
            const float f1 = floorf(s1);
            const uint32_t u0 = (uint32_t)f0;
            if (u0 >= lo && u0 < hiX) {
                const float r0 = s0 - f0;
                const float r1 = s1 - f1;
                const uint32_t ci = (u0 - lo) * R + (uint32_t)f1;
                const float2 q00 = sm[ci];
                const float2 q01 = sm[ci + 1u];
                const float2 q10 = sm[ci + R];
                const float2 q11 = sm[ci + R + 1u];
                const float w00 = (1.f - r0) * (1.f - r1);
                const float w01 = (1.f - r0) * r1;
                const float w10 = r0 * (1.f - r1);
                const float w11 = r0 * r1;
                ws05[(size_t)(plane * 6u + 5u) * NPTS + pt] = make_float2(
                    w00 * q00.x + w01 * q01.x + w10 * q10.x + w11 * q11.x,
                    w00 * q00.y + w01 * q01.y + w10 * q10.y + w11 * q11.y);
            }
        }
    }
}

// ---------------- K3: levels 12-15 direct gather, XCD-pinned (r9) ------------
__global__ __launch_bounds__(256) void k_hi(
    const float2* __restrict__ pts2, const float2* __restrict__ tab,
    float2* __restrict__ wsH)
{
    const uint32_t b = blockIdx.x, t = threadIdx.x;
    const uint32_t xcd = b & 7u;
    const uint32_t s   = b >> 3;             // 0..767
    uint32_t g, chunk;
    if (s < 512u) { g = xcd; chunk = s; }                    // groups 0-7 full
    else { g = 8u + (xcd >> 1); chunk = ((xcd & 1u) << 8) + (s - 512u); }
    const uint32_t plane = g % 3u;
    const uint32_t lvl   = 12u + g / 3u;
    const uint32_t gabs  = plane * 16u + lvl;
    const float    res   = c_res[lvl];
    const uint32_t tb    = gabs * TSIZE;
    const float4* __restrict__ tab4 = (const float4*)tab;
    const uint32_t b4    = gabs * (TSIZE / 2u);
    const float2* __restrict__ pp = pts2 + (size_t)plane * NPTS;
    const uint32_t pt0   = chunk * 1024u + t;

    float4 P0[4], P1[4];
    float2 Q0[4], Q1[4];
    float  r0[4], r1[4];
    uint32_t sel0[4], sel1[4], oddm[4];

#pragma unroll
    for (int k = 0; k < 4; ++k) {            // issue all loads first
        const uint32_t pt = pt0 + (uint32_t)k * 256u;
        const float2 c2 = pp[pt];
        const float s0 = c2.x * res;
        const float s1 = c2.y * res;
        const float f0 = floorf(s0);
        const float f1 = floorf(s1);
        r0[k] = s0 - f0;                     // exact f32 match to reference
        r1[k] = s1 - f1;
        const uint32_t u0  = (uint32_t)f0;
        const uint32_t hy0 = (uint32_t)f1 * PRIME1;
        const uint32_t hy1 = hy0 + PRIME1;
        const uint32_t i00 = ( u0        ^ hy0) & TMASK;
        const uint32_t i01 = ( u0        ^ hy1) & TMASK;
        const uint32_t i10 = ((u0 + 1u)  ^ hy0) & TMASK;
        const uint32_t i11 = ((u0 + 1u)  ^ hy1) & TMASK;
        sel0[k] = i00 & 1u;
        sel1[k] = i01 & 1u;
        oddm[k] = u0 & 1u;
        P0[k] = tab4[b4 + (i00 >> 1)];       // covers t00 (+t10 if u0 even)
        P1[k] = tab4[b4 + (i01 >> 1)];       // covers t01 (+t11 if u0 even)
        Q0[k] = make_float2(0.f, 0.f);
        Q1[k] = make_float2(0.f, 0.f);
        if (oddm[k]) {                       // exec-masked, ~50% lanes
            Q0[k] = tab[tb + i10];
            Q1[k] = tab[tb + i11];
        }
    }
#pragma unroll
    for (int k = 0; k < 4; ++k) {
        const uint32_t pt = pt0 + (uint32_t)k * 256u;
        const float2 lo0 = make_float2(P0[k].x, P0[k].y);
        const float2 hi0 = make_float2(P0[k].z, P0[k].w);
        const float2 lo1 = make_float2(P1[k].x, P1[k].y);
        const float2 hi1 = make_float2(P1[k].z, P1[k].w);
        const float2 t00 = sel0[k] ? hi0 : lo0;
        const float2 t01 = sel1[k] ? hi1 : lo1;
        const float2 t10 = oddm[k] ? Q0[k] : (sel0[k] ? lo0 : hi0);
        const float2 t11 = oddm[k] ? Q1[k] : (sel1[k] ? lo1 : hi1);
        const float w00 = (1.f - r0[k]) * (1.f - r1[k]);
        const float w01 = (1.f - r0[k]) * r1[k];
        const float w10 = r0[k] * (1.f - r1[k]);
        const float w11 = r0[k] * r1[k];
        wsH[(size_t)g * NPTS + pt] = make_float2(
            w00 * t00.x + w01 * t01.x + w10 * t10.x + w11 * t11.x,
            w00 * t00.y + w01 * t01.y + w10 * t10.y + w11 * t11.y);
    }
}

// ---------------- K4: combine -> out ------------------------------------------
__global__ __launch_bounds__(256) void k_comb(
    const float2* __restrict__ ws05, const float2* __restrict__ ws2,
    const float2* __restrict__ wsH, float2* __restrict__ out)
{
    __shared__ float2 s05[1152];             // 18 rows x 64 pts
    __shared__ float2 s2[1152];              // 64 pts x 18
    __shared__ float2 sh[768];               // 12 rows x 64 pts
    const uint32_t b = blockIdx.x, t = threadIdx.x;
    const uint32_t pt0 = b * 64u;
    for (uint32_t i = t; i < 1152u; i += 256u) {
        const uint32_t row = i >> 6, p = i & 63u;
        s05[i] = ws05[(size_t)row * NPTS + pt0 + p];
    }
    const float2* __restrict__ w2src = ws2 + (size_t)pt0 * 18u;
    for (uint32_t i = t; i < 1152u; i += 256u) s2[i] = w2src[i];
    for (uint32_t i = t; i < 768u; i += 256u) {
        const uint32_t row = i >> 6, p = i & 63u;
        sh[i] = wsH[(size_t)row * NPTS + pt0 + p];
    }
    __syncthreads();
#pragma unroll
    for (uint32_t k = 0; k < 4u; ++k) {
        const uint32_t e = t + k * 256u;
        const uint32_t pt = e >> 4, l = e & 15u;
        float2 v;
        if (l < 6u) {
            const float2 a  = s05[l * 64u + pt];
            const float2 bb = s05[(6u + l) * 64u + pt];
            const float2 c  = s05[(12u + l) * 64u + pt];
            v = make_float2(a.x * bb.x * c.x, a.y * bb.y * c.y);
        } else if (l < 12u) {
            const uint32_t j = l - 6u;
            const float2 a  = s2[pt * 18u + j];
            const float2 bb = s2[pt * 18u + 6u + j];
            const float2 c  = s2[pt * 18u + 12u + j];
            v = make_float2(a.x * bb.x * c.x, a.y * bb.y * c.y);
        } else {
            const uint32_t j0 = (l - 12u) * 3u;
            const float2 a  = sh[j0 * 64u + pt];
            const float2 bb = sh[(j0 + 1u) * 64u + pt];
            const float2 c  = sh[(j0 + 2u) * 64u + pt];
            v = make_float2(a.x * bb.x * c.x, a.y * bb.y * c.y);
        }
        out[(size_t)(pt0 + pt) * 16u + l] = v;
    }
}

// ---------------- Plan B fallback: r2 3-pass + transpose ---------------------
template <int P, bool FIRST>
__global__ __launch_bounds__(256) void kplane_pass(
    const float* __restrict__ pts, const float2* __restrict__ tab,
    float2* __restrict__ ws)
{
    const uint32_t b     = blockIdx.x;
    const uint32_t xcd   = b & 7u;
    const uint32_t s     = b >> 3;
    const uint32_t gi    = s >> 11;
    const uint32_t chunk = s & 2047u;
    const uint32_t lvl   = gi * 8u + xcd;
    const uint32_t pt    = chunk * 256u + threadIdx.x;
    constexpr int c0 = (P == 2) ? 1 : 0;
    constexpr int c1 = (P == 0) ? 1 : 2;
    const float a0  = pts[pt * 3u + c0];
    const float a1  = pts[pt * 3u + c1];
    const float res = c_res[lvl];
    const float s0 = a0 * res;
    const float s1 = a1 * res;
    const float f0 = floorf(s0);
    const float f1 = floorf(s1);
    const float r0 = s0 - f0;
    const float r1 = s1 - f1;
    const uint32_t u0 = (uint32_t)f0;
    const uint32_t hy0  = (uint32_t)f1 * PRIME1;
    const uint32_t hy1  = hy0 + PRIME1;
    const uint32_t base = ((uint32_t)P * 16u + lvl) * TSIZE;
    const float2 t00 = tab[base + (( u0       ^ hy0) & TMASK)];
    const float2 t01 = tab[base + (( u0       ^ hy1) & TMASK)];
    const float2 t10 = tab[base + (((u0 + 1u) ^ hy0) & TMASK)];
    const float2 t11 = tab[base + (((u0 + 1u) ^ hy1) & TMASK)];
    const float w00 = (1.f - r0) * (1.f - r1);
    const float w01 = (1.f - r0) * r1;
    const float w10 = r0 * (1.f - r1);
    const float w11 = r0 * r1;
    const float e0 = w00 * t00.x + w01 * t01.x + w10 * t10.x + w11 * t11.x;
    const float e1 = w00 * t00.y + w01 * t01.y + w10 * t10.y + w11 * t11.y;
    const uint32_t widx = lvl * NPTS + pt;
    if (FIRST) {
        ws[widx] = make_float2(e0, e1);
    } else {
        const float2 prev = ws[widx];
        ws[widx] = make_float2(prev.x * e0, prev.y * e1);
    }
}

__global__ __launch_bounds__(256) void kplane_transpose(
    const float2* __restrict__ ws, float2* __restrict__ out)
{
    const uint32_t tid = blockIdx.x * 256u + threadIdx.x;
    const uint32_t lvl = tid & 15u;
    const uint32_t pt  = tid >> 4;
    out[tid] = ws[lvl * NPTS + pt];
}

__global__ __launch_bounds__(256) void kplane_mono(
    const float* __restrict__ pts, const float2* __restrict__ tab,
    float2* __restrict__ out)
{
    const uint32_t tid = blockIdx.x * 256u + threadIdx.x;
    const uint32_t pt  = tid >> 4;
    const uint32_t lvl = tid & 15u;
    const float x = pts[pt * 3u + 0u];
    const float y = pts[pt * 3u + 1u];
    const float z = pts[pt * 3u + 2u];
    const float res = c_res[lvl];
    const float a0[3] = {x, x, y};
    const float a1[3] = {y, z, z};
    float p0 = 1.f, p1 = 1.f;
#pragma unroll
    for (int pl = 0; pl < 3; ++pl) {
        const float s0 = a0[pl] * res;
        const float s1 = a1[pl] * res;
        const float f0 = floorf(s0);
        const float f1 = floorf(s1);
        const float r0 = s0 - f0;
        const float r1 = s1 - f1;
        const uint32_t u0 = (uint32_t)f0;
        const uint32_t hy0 = (uint32_t)f1 * PRIME1;
        const uint32_t hy1 = hy0 + PRIME1;
        const uint32_t base = ((uint32_t)pl * 16u + lvl) * TSIZE;
        const float2 t00 = tab[base + (( u0       ^ hy0) & TMASK)];
        const float2 t01 = tab[base + (( u0       ^ hy1) & TMASK)];
        const float2 t10 = tab[base + (((u0 + 1u) ^ hy0) & TMASK)];
        const float2 t11 = tab[base + (((u0 + 1u) ^ hy1) & TMASK)];
        const float w00 = (1.f - r0) * (1.f - r1);
        const float w01 = (1.f - r0) * r1;
        const float w10 = r0 * (1.f - r1);
        const float w11 = r0 * r1;
        p0 *= w00 * t00.x + w01 * t01.x + w10 * t10.x + w11 * t11.x;
        p1 *= w00 * t00.y + w01 * t01.y + w10 * t10.y + w11 * t11.y;
    }
    out[pt * 16u + lvl] = make_float2(p0, p1);
}

extern "C" void kernel_launch(void* const* d_in, const int* in_sizes, int n_in,
                              void* d_out, int out_size, void* d_ws, size_t ws_size,
                              hipStream_t stream) {
    const float*  pts = (const float*)d_in[0];
    const float2* tab = (const float2*)d_in[1];
    float2*       out = (float2*)d_out;

    const size_t wsA = (size_t)48 * NPTS * sizeof(float2);   // 201.3 MB
    const size_t wsB = (size_t)16 * NPTS * sizeof(float2);   //  67.1 MB
    dim3 block256(256u);

    if (ws_size >= wsA) {
        // d_out scratch: pts2 (12.6MB) | sort16 (25.2MB) | hist | cursor
        float2*   pts2   = (float2*)d_out;
        float4*   sort16 = (float4*)(pts2 + (size_t)3 * NPTS);
        uint32_t* hist   = (uint32_t*)(sort16 + (size_t)3 * NPTS);
        uint32_t* cursor = hist + 768;
        // d_ws: ws05 (18,NPTS) | ws2 (NPTS,18) | wsH (12,NPTS)
        float2* ws05 = (float2*)d_ws;
        float2* ws2  = ws05 + (size_t)18 * NPTS;
        float2* wsH  = ws2  + (size_t)18 * NPTS;

        hipMemsetAsync(hist, 0, 1536u * sizeof(uint32_t), stream);
        hipLaunchKernelGGL(k_packhist, dim3(2048u), block256, 0, stream,
                           pts, pts2, hist);
        hipLaunchKernelGGL(k_scatter,  dim3(192u),  block256, 0, stream,
                           pts2, hist, cursor, sort16);
        hipLaunchKernelGGL(k_lowmid,   dim3(1152u), block256, 0, stream,
                           pts2, sort16, hist, tab, ws05, ws2);
        hipLaunchKernelGGL(k_hi,       dim3(6144u), block256, 0, stream,
                           pts2, tab, wsH);
        hipLaunchKernelGGL(k_comb,     dim3(NPTS / 64u), block256, 0, stream,
                           ws05, ws2, wsH, out);
    } else if (ws_size >= wsB) {
        float2* ws = (float2*)d_ws;
        dim3 grid(16u * (NPTS / 256u));
        hipLaunchKernelGGL((kplane_pass<0, true >), grid, block256, 0, stream, pts, tab, ws);
        hipLaunchKernelGGL((kplane_pass<1, false>), grid, block256, 0, stream, pts, tab, ws);
        hipLaunchKernelGGL((kplane_pass<2, false>), grid, block256, 0, stream, pts, tab, ws);
        dim3 tgrid((NPTS * 16u) / 256u);
        hipLaunchKernelGGL(kplane_transpose, tgrid, block256, 0, stream, ws, out);
    } else {
        dim3 grid((NPTS * 16u) / 256u);
        hipLaunchKernelGGL(kplane_mono, grid, block256, 0, stream, pts, tab, out);
    }
}

// Round 13
// 266.105 us; speedup vs baseline: 1.2743x; 1.1795x over previous
//
#include <hip/hip_runtime.h>
#include <hip/hip_fp16.h>
#include <stdint.h>

// K-Planes hash-grid encoder, MI355X.  Round 13.
// Model: divergent vector-memory requests ~4.6us/M (while 1 table/XCD-L2),
// scattered stores count, additive system-wide. r9/r10/r12 floor = front 25
// + low 90 + hi 90 + comb 42. This round deletes ledger items:
//  - dense-expand l0-11 once (2M divergent, 9us) -> bucket staging coalesced
//  - f16 intermediates: low 6->3 scattered stores/pt/plane; comb 200->100MB
//  - one uniform low region (768 blocks, no lds05 tail)
// Pipeline: memset | k_packexp (pack pts2 + hist + dense-expand) | k_scatter
//           | k_low (l0-11 bucket-LDS, f16 out) | k_hi (l12-15, r9 body,
//           f16 out) | k_comb (join, f16 in, f32 out)
// Fallbacks: Plan B (r2 3-pass + transpose), mono.

#define NPTS   524288u
#define TSIZE  524288u
#define TMASK  0x7FFFFu
#define PRIME1 2654435761u
#define PLANE_D     663817u
#define DENSE_TOTAL 1991451u

__constant__ float c_res[16] = {
    16.f, 22.f, 30.f, 42.f, 58.f, 80.f, 111.f, 153.f,
    212.f, 294.f, 406.f, 561.f, 775.f, 1072.f, 1481.f, 2047.f
};
__constant__ int      c_resiLow[12] = {16, 22, 30, 42, 58, 80, 111, 153, 212, 294, 406, 561};
__constant__ uint32_t c_RD[12]   = {17, 23, 31, 43, 59, 81, 112, 154, 213, 295, 407, 562};
__constant__ uint32_t c_offD[12] = {0, 289, 818, 1779, 3628, 7109, 13670,
                                    26214, 49930, 95299, 182324, 347973};

__device__ __forceinline__ uint32_t pkh2(float a, float b) {
    __half2 h2;
    h2.x = __float2half_rn(a);
    h2.y = __float2half_rn(b);
    return *reinterpret_cast<const uint32_t*>(&h2);
}
__device__ __forceinline__ float2 uph2(uint32_t u) {
    __half2 h2 = *reinterpret_cast<const __half2*>(&u);
    return make_float2(__half2float(h2.x), __half2float(h2.y));
}

// ---------------- K0: pack pts2 + bucket histograms + dense expand ----------
__global__ __launch_bounds__(256) void k_packexp(
    const float* __restrict__ pts, const float2* __restrict__ tab,
    float2* __restrict__ pts2, uint32_t* __restrict__ hist,
    float2* __restrict__ dense)
{
    __shared__ uint32_t lh[768];
    const uint32_t b = blockIdx.x, t = threadIdx.x;

    if (b >= 2048u) {                        // dense-expand region
        const uint32_t idx = (b - 2048u) * 256u + t;
        if (idx >= DENSE_TOTAL) return;
        const uint32_t plane = idx / PLANE_D;
        const uint32_t i     = idx - plane * PLANE_D;
        uint32_t lvl = 11u;
        while (i < c_offD[lvl]) lvl--;
        const uint32_t RD    = c_RD[lvl];
        const uint32_t local = i - c_offD[lvl];
        const uint32_t cx = local / RD, cy = local - cx * RD;
        dense[idx] =
            tab[(plane * 16u + lvl) * TSIZE + ((cx ^ (cy * PRIME1)) & TMASK)];
        return;
    }

    lh[t] = 0u; lh[t + 256u] = 0u; lh[t + 512u] = 0u;
    __syncthreads();
    const uint32_t pt = b * 256u + t;
    const float x = pts[pt * 3u + 0u];
    const float y = pts[pt * 3u + 1u];
    const float z = pts[pt * 3u + 2u];
    pts2[            pt] = make_float2(x, y);
    pts2[NPTS      + pt] = make_float2(x, z);
    pts2[2u * NPTS + pt] = make_float2(y, z);
    const uint32_t bx = min(15u, (uint32_t)(x * 16.f));
    const uint32_t by = min(15u, (uint32_t)(y * 16.f));
    const uint32_t bz = min(15u, (uint32_t)(z * 16.f));
    atomicAdd(&lh[         bx * 16u + by], 1u);
    atomicAdd(&lh[256u +   bx * 16u + bz], 1u);
    atomicAdd(&lh[512u +   by * 16u + bz], 1u);
    __syncthreads();
    if (lh[t])        atomicAdd(&hist[t],        lh[t]);
    if (lh[t + 256u]) atomicAdd(&hist[t + 256u], lh[t + 256u]);
    if (lh[t + 512u]) atomicAdd(&hist[t + 512u], lh[t + 512u]);
}

// ---------------- K1: counting-sort scatter (local scan) --------------------
__global__ __launch_bounds__(256) void k_scatter(
    const float2* __restrict__ pts2, const uint32_t* __restrict__ hist,
    uint32_t* __restrict__ cursor, float4* __restrict__ sort16)
{
    __shared__ uint32_t su[256], lcnt[256], gb[256], lc2[256];
    const uint32_t b = blockIdx.x, t = threadIdx.x;
    const uint32_t plane = b >> 6, chunk = b & 63u;
    const uint32_t h = hist[plane * 256u + t];
    su[t] = h; lcnt[t] = 0u; lc2[t] = 0u;
    __syncthreads();
    for (uint32_t off = 1u; off < 256u; off <<= 1) {
        uint32_t v = 0u;
        if (t >= off) v = su[t - off];
        __syncthreads();
        su[t] += v;
        __syncthreads();
    }
    const uint32_t mybase = su[t] - h;
    const float2* __restrict__ pp = pts2 + (size_t)plane * NPTS;
    const uint32_t pt0 = chunk * 8192u + t;
    for (uint32_t k = 0; k < 32u; ++k) {
        const float2 c = pp[pt0 + k * 256u];
        const uint32_t bb = min(15u, (uint32_t)(c.x * 16.f)) * 16u
                          + min(15u, (uint32_t)(c.y * 16.f));
        atomicAdd(&lcnt[bb], 1u);
    }
    __syncthreads();
    gb[t] = mybase + atomicAdd(&cursor[plane * 256u + t], lcnt[t]);
    __syncthreads();
    float4* __restrict__ sp = sort16 + (size_t)plane * NPTS;
    for (uint32_t k = 0; k < 32u; ++k) {
        const uint32_t pt = pt0 + k * 256u;
        const float2 c = pp[pt];
        const uint32_t bb = min(15u, (uint32_t)(c.x * 16.f)) * 16u
                          + min(15u, (uint32_t)(c.y * 16.f));
        const uint32_t r = atomicAdd(&lc2[bb], 1u);
        sp[gb[bb] + r] = make_float4(c.x, c.y, __uint_as_float(pt), 0.f);
    }
}

// ---------------- K2: levels 0-11 per (plane,bucket), dense staging, f16 ----
__global__ __launch_bounds__(256) void k_low(
    const float4* __restrict__ sort16, const uint32_t* __restrict__ hist,
    const float2* __restrict__ dense, uint4* __restrict__ ws2u)
{
    __shared__ float2 sm[4000];              // worst-case rect sum 3961
    __shared__ uint32_t Poff[12], Pu0[12], Pu1[12], Pcols[12], Prows[12];
    const uint32_t b = blockIdx.x, t = threadIdx.x;
    const uint32_t plane  = b >> 8;
    const uint32_t bucket = b & 255u;
    const uint32_t bx = bucket >> 4, by = bucket & 15u;

    uint32_t* su = (uint32_t*)sm;            // scan ws aliases staging buf
    const uint32_t h = hist[plane * 256u + t];
    su[t] = h;
    __syncthreads();
    for (uint32_t off = 1u; off < 256u; off <<= 1) {
        uint32_t v = 0u;
        if (t >= off) v = su[t - off];
        __syncthreads();
        su[t] += v;
        __syncthreads();
    }
    const uint32_t cntB  = hist[plane * 256u + bucket];
    const uint32_t start = su[bucket] - cntB;
    __syncthreads();

    if (t == 0u) {                           // rect metadata (r9 margins)
        uint32_t off = 0u;
        for (uint32_t l = 0; l < 12u; ++l) {
            const int R = c_resiLow[l];
            const int u0s = max(0, (int)((bx * (uint32_t)R) >> 4) - 1);
            const int u0e = min(R, (int)(((bx + 1u) * (uint32_t)R) >> 4) + 2);
            const int u1s = max(0, (int)((by * (uint32_t)R) >> 4) - 1);
            const int u1e = min(R, (int)(((by + 1u) * (uint32_t)R) >> 4) + 2);
            const uint32_t rows = (uint32_t)(u0e - u0s + 1);
            const uint32_t cols = (uint32_t)(u1e - u1s + 1);
            Poff[l] = off; Pu0[l] = (uint32_t)u0s; Pu1[l] = (uint32_t)u1s;
            Pcols[l] = cols; Prows[l] = rows;
            off += rows * cols;
        }
    }
    __syncthreads();

    const size_t pbase = (size_t)plane * PLANE_D;
    for (uint32_t l = 0; l < 12u; ++l) {     // COALESCED staging from dense
        const uint32_t off = Poff[l], u0s = Pu0[l], u1s = Pu1[l];
        const uint32_t cols = Pcols[l];
        const uint32_t E = Prows[l] * cols;
        const uint32_t RD = c_RD[l];
        const size_t dbase = pbase + c_offD[l];
        for (uint32_t i = t; i < E; i += 256u) {
            const uint32_t r  = i / cols;
            const uint32_t cx = u0s + r;
            const uint32_t cy = u1s + (i - r * cols);
            sm[off + i] = dense[dbase + (size_t)cx * RD + cy];
        }
    }
    __syncthreads();

    const float4* __restrict__ sp = sort16 + (size_t)plane * NPTS;
    for (uint32_t i = t; i < cntB; i += 256u) {
        const float4 f = sp[start + i];
        const float c0 = f.x, c1 = f.y;
        const uint32_t orig = __float_as_uint(f.z);
        uint32_t hp[12];
#pragma unroll
        for (int l = 0; l < 12; ++l) {
            const float res = c_res[l];
            const float s0 = c0 * res;
            const float s1 = c1 * res;
            const float f0 = floorf(s0);
            const float f1 = floorf(s1);
            const float r0 = s0 - f0;        // exact f32 interp (f16 only at store)
            const float r1 = s1 - f1;
            const uint32_t u0 = (uint32_t)f0, u1 = (uint32_t)f1;
            const uint32_t cols = Pcols[l];
            const uint32_t ci = Poff[l] + (u0 - Pu0[l]) * cols + (u1 - Pu1[l]);
            const float2 q00 = sm[ci];
            const float2 q01 = sm[ci + 1u];
            const float2 q10 = sm[ci + cols];
            const float2 q11 = sm[ci + cols + 1u];
            const float w00 = (1.f - r0) * (1.f - r1);
            const float w01 = (1.f - r0) * r1;
            const float w10 = r0 * (1.f - r1);
            const float w11 = r0 * r1;
            hp[l] = pkh2(
                w00 * q00.x + w01 * q01.x + w10 * q10.x + w11 * q11.x,
                w00 * q00.y + w01 * q01.y + w10 * q10.y + w11 * q11.y);
        }
        const size_t d = ((size_t)orig * 3u + plane) * 3u;
        ws2u[d + 0] = make_uint4(hp[0], hp[1], hp[2],  hp[3]);
        ws2u[d + 1] = make_uint4(hp[4], hp[5], hp[6],  hp[7]);
        ws2u[d + 2] = make_uint4(hp[8], hp[9], hp[10], hp[11]);
    }
}

// ---------------- K3: levels 12-15 direct gather, XCD-pinned (r9), f16 out --
__global__ __launch_bounds__(256) void k_hi(
    const float2* __restrict__ pts2, const float2* __restrict__ tab,
    uint32_t* __restrict__ wsHh)
{
    const uint32_t b = blockIdx.x, t = threadIdx.x;
    const uint32_t xcd = b & 7u;
    const uint32_t s   = b >> 3;             // 0..767
    uint32_t g, chunk;
    if (s < 512u) { g = xcd; chunk = s; }                    // groups 0-7 full
    else { g = 8u + (xcd >> 1); chunk = ((xcd & 1u) << 8) + (s - 512u); }
    const uint32_t plane = g % 3u;
    const uint32_t lvl   = 12u + g / 3u;
    const uint32_t gabs  = plane * 16u + lvl;
    const float    res   = c_res[lvl];
    const uint32_t tb    = gabs * TSIZE;
    const float4* __restrict__ tab4 = (const float4*)tab;
    const uint32_t b4    = gabs * (TSIZE / 2u);
    const float2* __restrict__ pp = pts2 + (size_t)plane * NPTS;
    const uint32_t pt0   = chunk * 1024u + t;

    float4 P0[4], P1[4];
    float2 Q0[4], Q1[4];
    float  r0[4], r1[4];
    uint32_t sel0[4], sel1[4], oddm[4];

#pragma unroll
    for (int k = 0; k < 4; ++k) {            // issue all loads first
        const uint32_t pt = pt0 + (uint32_t)k * 256u;
        const float2 c2 = pp[pt];
        const float s0 = c2.x * res;
        const float s1 = c2.y * res;
        const float f0 = floorf(s0);
        const float f1 = floorf(s1);
        r0[k] = s0 - f0;                     // exact f32 match to reference
        r1[k] = s1 - f1;
        const uint32_t u0  = (uint32_t)f0;
        const uint32_t hy0 = (uint32_t)f1 * PRIME1;
        const uint32_t hy1 = hy0 + PRIME1;
        const uint32_t i00 = ( u0        ^ hy0) & TMASK;
        const uint32_t i01 = ( u0        ^ hy1) & TMASK;
        const uint32_t i10 = ((u0 + 1u)  ^ hy0) & TMASK;
        const uint32_t i11 = ((u0 + 1u)  ^ hy1) & TMASK;
        sel0[k] = i00 & 1u;
        sel1[k] = i01 & 1u;
        oddm[k] = u0 & 1u;
        P0[k] = tab4[b4 + (i00 >> 1)];       // covers t00 (+t10 if u0 even)
        P1[k] = tab4[b4 + (i01 >> 1)];       // covers t01 (+t11 if u0 even)
        Q0[k] = make_float2(0.f, 0.f);
        Q1[k] = make_float2(0.f, 0.f);
        if (oddm[k]) {                       // exec-masked, ~50% lanes
            Q0[k] = tab[tb + i10];
            Q1[k] = tab[tb + i11];
        }
    }
#pragma unroll
    for (int k = 0; k < 4; ++k) {
        const uint32_t pt = pt0 + (uint32_t)k * 256u;
        const float2 lo0 = make_float2(P0[k].x, P0[k].y);
        const float2 hi0 = make_float2(P0[k].z, P0[k].w);
        const float2 lo1 = make_float2(P1[k].x, P1[k].y);
        const float2 hi1 = make_float2(P1[k].z, P1[k].w);
        const float2 t00 = sel0[k] ? hi0 : lo0;
        const float2 t01 = sel1[k] ? hi1 : lo1;
        const float2 t10 = oddm[k] ? Q0[k] : (sel0[k] ? lo0 : hi0);
        const float2 t11 = oddm[k] ? Q1[k] : (sel1[k] ? lo1 : hi1);
        const float w00 = (1.f - r0[k]) * (1.f - r1[k]);
        const float w01 = (1.f - r0[k]) * r1[k];
        const float w10 = r0[k] * (1.f - r1[k]);
        const float w11 = r0[k] * r1[k];
        wsHh[(size_t)g * NPTS + pt] = pkh2(
            w00 * t00.x + w01 * t01.x + w10 * t10.x + w11 * t11.x,
            w00 * t00.y + w01 * t01.y + w10 * t10.y + w11 * t11.y);
    }
}

// ---------------- K4: combine (f16 in) -> out (f32) --------------------------
__global__ __launch_bounds__(256) void k_comb(
    const uint4* __restrict__ ws2u, const uint32_t* __restrict__ wsHh,
    float2* __restrict__ out)
{
    __shared__ uint32_t s2[2304];            // 64 pts x 36 uints (9 uint4)
    __shared__ uint32_t sh[768];             // 12 g x 64 pts
    const uint32_t b = blockIdx.x, t = threadIdx.x;
    const uint32_t pt0 = b * 64u;
    uint4* s4 = (uint4*)s2;
    for (uint32_t i = t; i < 576u; i += 256u)
        s4[i] = ws2u[(size_t)pt0 * 9u + i];
    for (uint32_t i = t; i < 768u; i += 256u) {
        const uint32_t g = i >> 6, p = i & 63u;
        sh[i] = wsHh[(size_t)g * NPTS + pt0 + p];
    }
    __syncthreads();
#pragma unroll
    for (uint32_t k = 0; k < 4u; ++k) {
        const uint32_t e = t + k * 256u;
        const uint32_t pt = e >> 4, l = e & 15u;
        float2 v;
        if (l < 12u) {
            const float2 a  = uph2(s2[pt * 36u + l]);
            const float2 bb = uph2(s2[pt * 36u + 12u + l]);
            const float2 c  = uph2(s2[pt * 36u + 24u + l]);
            v = make_float2(a.x * bb.x * c.x, a.y * bb.y * c.y);
        } else {
            const uint32_t j0 = (l - 12u) * 3u;
            const float2 a  = uph2(sh[j0 * 64u + pt]);
            const float2 bb = uph2(sh[(j0 + 1u) * 64u + pt]);
            const float2 c  = uph2(sh[(j0 + 2u) * 64u + pt]);
            v = make_float2(a.x * bb.x * c.x, a.y * bb.y * c.y);
        }
        out[(size_t)(pt0 + pt) * 16u + l] = v;
    }
}

// ---------------- Plan B fallback: r2 3-pass + transpose ---------------------
template <int P, bool FIRST>
__global__ __launch_bounds__(256) void kplane_pass(
    const float* __restrict__ pts, const float2* __restrict__ tab,
    float2* __restrict__ ws)
{
    const uint32_t b     = blockIdx.x;
    const uint32_t xcd   = b & 7u;
    const uint32_t s     = b >> 3;
    const uint32_t gi    = s >> 11;
    const uint32_t chunk = s & 2047u;
    const uint32_t lvl   = gi * 8u + xcd;
    const uint32_t pt    = chunk * 256u + threadIdx.x;
    constexpr int c0 = (P == 2) ? 1 : 0;
    constexpr int c1 = (P == 0) ? 1 : 2;
    const float a0  = pts[pt * 3u + c0];
    const float a1  = pts[pt * 3u + c1];
    const float res = c_res[lvl];
    const float s0 = a0 * res;
    const float s1 = a1 * res;
    const float f0 = floorf(s0);
    const float f1 = floorf(s1);
    const float r0 = s0 - f0;
    const float r1 = s1 - f1;
    const uint32_t u0 = (uint32_t)f0;
    const uint32_t hy0  = (uint32_t)f1 * PRIME1;
    const uint32_t hy1  = hy0 + PRIME1;
    const uint32_t base = ((uint32_t)P * 16u + lvl) * TSIZE;
    const float2 t00 = tab[base + (( u0       ^ hy0) & TMASK)];
    const float2 t01 = tab[base + (( u0       ^ hy1) & TMASK)];
    const float2 t10 = tab[base + (((u0 + 1u) ^ hy0) & TMASK)];
    const float2 t11 = tab[base + (((u0 + 1u) ^ hy1) & TMASK)];
    const float w00 = (1.f - r0) * (1.f - r1);
    const float w01 = (1.f - r0) * r1;
    const float w10 = r0 * (1.f - r1);
    const float w11 = r0 * r1;
    const float e0 = w00 * t00.x + w01 * t01.x + w10 * t10.x + w11 * t11.x;
    const float e1 = w00 * t00.y + w01 * t01.y + w10 * t10.y + w11 * t11.y;
    const uint32_t widx = lvl * NPTS + pt;
    if (FIRST) {
        ws[widx] = make_float2(e0, e1);
    } else {
        const float2 prev = ws[widx];
        ws[widx] = make_float2(prev.x * e0, prev.y * e1);
    }
}

__global__ __launch_bounds__(256) void kplane_transpose(
    const float2* __restrict__ ws, float2* __restrict__ out)
{
    const uint32_t tid = blockIdx.x * 256u + threadIdx.x;
    const uint32_t lvl = tid & 15u;
    const uint32_t pt  = tid >> 4;
    out[tid] = ws[lvl * NPTS + pt];
}

__global__ __launch_bounds__(256) void kplane_mono(
    const float* __restrict__ pts, const float2* __restrict__ tab,
    float2* __restrict__ out)
{
    const uint32_t tid = blockIdx.x * 256u + threadIdx.x;
    const uint32_t pt  = tid >> 4;
    const uint32_t lvl = tid & 15u;
    const float x = pts[pt * 3u + 0u];
    const float y = pts[pt * 3u + 1u];
    const float z = pts[pt * 3u + 2u];
    const float res = c_res[lvl];
    const float a0[3] = {x, x, y};
    const float a1[3] = {y, z, z};
    float p0 = 1.f, p1 = 1.f;
#pragma unroll
    for (int pl = 0; pl < 3; ++pl) {
        const float s0 = a0[pl] * res;
        const float s1 = a1[pl] * res;
        const float f0 = floorf(s0);
        const float f1 = floorf(s1);
        const float r0 = s0 - f0;
        const float r1 = s1 - f1;
        const uint32_t u0 = (uint32_t)f0;
        const uint32_t hy0 = (uint32_t)f1 * PRIME1;
        const uint32_t hy1 = hy0 + PRIME1;
        const uint32_t base = ((uint32_t)pl * 16u + lvl) * TSIZE;
        const float2 t00 = tab[base + (( u0       ^ hy0) & TMASK)];
        const float2 t01 = tab[base + (( u0       ^ hy1) & TMASK)];
        const float2 t10 = tab[base + (((u0 + 1u) ^ hy0) & TMASK)];
        const float2 t11 = tab[base + (((u0 + 1u) ^ hy1) & TMASK)];
        const float w00 = (1.f - r0) * (1.f - r1);
        const float w01 = (1.f - r0) * r1;
        const float w10 = r0 * (1.f - r1);
        const float w11 = r0 * r1;
        p0 *= w00 * t00.x + w01 * t01.x + w10 * t10.x + w11 * t11.x;
        p1 *= w00 * t00.y + w01 * t01.y + w10 * t10.y + w11 * t11.y;
    }
    out[pt * 16u + lvl] = make_float2(p0, p1);
}

extern "C" void kernel_launch(void* const* d_in, const int* in_sizes, int n_in,
                              void* d_out, int out_size, void* d_ws, size_t ws_size,
                              hipStream_t stream) {
    const float*  pts = (const float*)d_in[0];
    const float2* tab = (const float2*)d_in[1];
    float2*       out = (float2*)d_out;

    const size_t wsA = (size_t)NPTS * 192u;                  // 100.7 MB
    const size_t wsB = (size_t)16 * NPTS * sizeof(float2);   //  67.1 MB
    dim3 block256(256u);

    if (ws_size >= wsA) {
        // d_out scratch: pts2 12.6MB | sort16 25.2MB | dense 15.9MB | hist
        float2*   pts2   = (float2*)d_out;
        float4*   sort16 = (float4*)(pts2 + (size_t)3 * NPTS);
        float2*   dense  = (float2*)(sort16 + (size_t)3 * NPTS);
        uint32_t* hist   = (uint32_t*)(dense + DENSE_TOTAL);
        uint32_t* cursor = hist + 768;
        // d_ws: ws2u (NPTS x 9 uint4, 75.5MB) | wsHh (12 x NPTS uint, 25.2MB)
        uint4*    ws2u   = (uint4*)d_ws;
        uint32_t* wsHh   = (uint32_t*)(ws2u + (size_t)NPTS * 9u);

        hipMemsetAsync(hist, 0, 1536u * sizeof(uint32_t), stream);
        hipLaunchKernelGGL(k_packexp, dim3(2048u + 7780u), block256, 0, stream,
                           pts, tab, pts2, hist, dense);
        hipLaunchKernelGGL(k_scatter, dim3(192u),  block256, 0, stream,
                           pts2, hist, cursor, sort16);
        hipLaunchKernelGGL(k_low,     dim3(768u),  block256, 0, stream,
                           sort16, hist, dense, ws2u);
        hipLaunchKernelGGL(k_hi,      dim3(6144u), block256, 0, stream,
                           pts2, tab, wsHh);
        hipLaunchKernelGGL(k_comb,    dim3(NPTS / 64u), block256, 0, stream,
                           ws2u, wsHh, out);
    } else if (ws_size >= wsB) {
        float2* ws = (float2*)d_ws;
        dim3 grid(16u * (NPTS / 256u));
        hipLaunchKernelGGL((kplane_pass<0, true >), grid, block256, 0, stream, pts, tab, ws);
        hipLaunchKernelGGL((kplane_pass<1, false>), grid, block256, 0, stream, pts, tab, ws);
        hipLaunchKernelGGL((kplane_pass<2, false>), grid, block256, 0, stream, pts, tab, ws);
        dim3 tgrid((NPTS * 16u) / 256u);
        hipLaunchKernelGGL(kplane_transpose, tgrid, block256, 0, stream, ws, out);
    } else {
        dim3 grid((NPTS * 16u) / 256u);
        hipLaunchKernelGGL(kplane_mono, grid, block256, 0, stream, pts, tab, out);
    }
}

// Round 14
// 232.277 us; speedup vs baseline: 1.4599x; 1.1456x over previous
//
#include <hip/hip_runtime.h>
#include <hip/hip_fp16.h>
#include <stdint.h>

// K-Planes hash-grid encoder, MI355X.  Round 14.
// = r9 skeleton (252us, best) + individually-proven deltas ONLY:
//   front fused (r10), f16 ws2 stores 6->3 scattered (r13-verified numerics),
//   f16 wsH, f16 comb. No dense-expand (r13 regression), no region fusion
//   (r8/r10/r12 regressions), hi untouched (r9 verbatim).
// Model: divergent vector-memory requests ~4.6us/M (1 table per XCD-L2),
// scattered stores count, additive; ~80% of 8-XCD x 16-ch L2 request rate.
//  memset | k_packhist | k_scatter | k_low (l0-11 bucket-LDS, f16 out)
//         | k_hi (l12-15 r9 body, f16 out) | k_comb (f16 in, f32 out)
// Fallbacks: Plan B (r2 3-pass + transpose), mono.

#define NPTS   524288u
#define TSIZE  524288u
#define TMASK  0x7FFFFu
#define PRIME1 2654435761u

__constant__ float c_res[16] = {
    16.f, 22.f, 30.f, 42.f, 58.f, 80.f, 111.f, 153.f,
    212.f, 294.f, 406.f, 561.f, 775.f, 1072.f, 1481.f, 2047.f
};
__constant__ int c_resiLow[12] = {16, 22, 30, 42, 58, 80, 111, 153, 212, 294, 406, 561};

__device__ __forceinline__ uint32_t pkh2(float a, float b) {
    __half2 h2;
    h2.x = __float2half_rn(a);
    h2.y = __float2half_rn(b);
    return *reinterpret_cast<const uint32_t*>(&h2);
}
__device__ __forceinline__ float2 uph2(uint32_t u) {
    __half2 h2 = *reinterpret_cast<const __half2*>(&u);
    return make_float2(__half2float(h2.x), __half2float(h2.y));
}

// ---------------- K0: pack per-plane coords + bucket histograms (r10) -------
__global__ __launch_bounds__(256) void k_packhist(
    const float* __restrict__ pts, float2* __restrict__ pts2,
    uint32_t* __restrict__ hist)
{
    __shared__ uint32_t lh[768];
    const uint32_t b = blockIdx.x, t = threadIdx.x;
    lh[t] = 0u; lh[t + 256u] = 0u; lh[t + 512u] = 0u;
    __syncthreads();
    const uint32_t pt = b * 256u + t;
    const float x = pts[pt * 3u + 0u];
    const float y = pts[pt * 3u + 1u];
    const float z = pts[pt * 3u + 2u];
    pts2[            pt] = make_float2(x, y);
    pts2[NPTS      + pt] = make_float2(x, z);
    pts2[2u * NPTS + pt] = make_float2(y, z);
    const uint32_t bx = min(15u, (uint32_t)(x * 16.f));
    const uint32_t by = min(15u, (uint32_t)(y * 16.f));
    const uint32_t bz = min(15u, (uint32_t)(z * 16.f));
    atomicAdd(&lh[         bx * 16u + by], 1u);
    atomicAdd(&lh[256u +   bx * 16u + bz], 1u);
    atomicAdd(&lh[512u +   by * 16u + bz], 1u);
    __syncthreads();
    if (lh[t])        atomicAdd(&hist[t],        lh[t]);
    if (lh[t + 256u]) atomicAdd(&hist[t + 256u], lh[t + 256u]);
    if (lh[t + 512u]) atomicAdd(&hist[t + 512u], lh[t + 512u]);
}

// ---------------- K1: counting-sort scatter, local scan (r10) ----------------
__global__ __launch_bounds__(256) void k_scatter(
    const float2* __restrict__ pts2, const uint32_t* __restrict__ hist,
    uint32_t* __restrict__ cursor, float4* __restrict__ sort16)
{
    __shared__ uint32_t su[256], lcnt[256], gb[256], lc2[256];
    const uint32_t b = blockIdx.x, t = threadIdx.x;
    const uint32_t plane = b >> 6, chunk = b & 63u;
    const uint32_t h = hist[plane * 256u + t];
    su[t] = h; lcnt[t] = 0u; lc2[t] = 0u;
    __syncthreads();
    for (uint32_t off = 1u; off < 256u; off <<= 1) {
        uint32_t v = 0u;
        if (t >= off) v = su[t - off];
        __syncthreads();
        su[t] += v;
        __syncthreads();
    }
    const uint32_t mybase = su[t] - h;
    const float2* __restrict__ pp = pts2 + (size_t)plane * NPTS;
    const uint32_t pt0 = chunk * 8192u + t;
    for (uint32_t k = 0; k < 32u; ++k) {
        const float2 c = pp[pt0 + k * 256u];
        const uint32_t bb = min(15u, (uint32_t)(c.x * 16.f)) * 16u
                          + min(15u, (uint32_t)(c.y * 16.f));
        atomicAdd(&lcnt[bb], 1u);
    }
    __syncthreads();
    gb[t] = mybase + atomicAdd(&cursor[plane * 256u + t], lcnt[t]);
    __syncthreads();
    float4* __restrict__ sp = sort16 + (size_t)plane * NPTS;
    for (uint32_t k = 0; k < 32u; ++k) {
        const uint32_t pt = pt0 + k * 256u;
        const float2 c = pp[pt];
        const uint32_t bb = min(15u, (uint32_t)(c.x * 16.f)) * 16u
                          + min(15u, (uint32_t)(c.y * 16.f));
        const uint32_t r = atomicAdd(&lc2[bb], 1u);
        sp[gb[bb] + r] = make_float4(c.x, c.y, __uint_as_float(pt), 0.f);
    }
}

// ---------------- K2: levels 0-11 per (plane,bucket), r9 body, f16 out ------
__global__ __launch_bounds__(256) void k_low(
    const float2* __restrict__ tab, const float4* __restrict__ sort16,
    const uint32_t* __restrict__ hist, uint4* __restrict__ ws2u)
{
    __shared__ float2 sm[4000];              // worst-case rect sum 3961
    __shared__ uint32_t Poff[12], Pu0[12], Pu1[12], Pcols[12], Prows[12];
    const uint32_t b = blockIdx.x, t = threadIdx.x;
    const uint32_t plane  = b >> 8;
    const uint32_t bucket = b & 255u;
    const uint32_t bx = bucket >> 4, by = bucket & 15u;

    uint32_t* su = (uint32_t*)sm;            // scan ws aliases staging buf
    const uint32_t h = hist[plane * 256u + t];
    su[t] = h;
    __syncthreads();
    for (uint32_t off = 1u; off < 256u; off <<= 1) {
        uint32_t v = 0u;
        if (t >= off) v = su[t - off];
        __syncthreads();
        su[t] += v;
        __syncthreads();
    }
    const uint32_t cntB  = hist[plane * 256u + bucket];
    const uint32_t start = su[bucket] - cntB;
    __syncthreads();

    if (t == 0u) {                           // rect metadata (r9 margins)
        uint32_t off = 0u;
        for (uint32_t l = 0; l < 12u; ++l) {
            const int R = c_resiLow[l];
            const int u0s = max(0, (int)((bx * (uint32_t)R) >> 4) - 1);
            const int u0e = min(R, (int)(((bx + 1u) * (uint32_t)R) >> 4) + 2);
            const int u1s = max(0, (int)((by * (uint32_t)R) >> 4) - 1);
            const int u1e = min(R, (int)(((by + 1u) * (uint32_t)R) >> 4) + 2);
            const uint32_t rows = (uint32_t)(u0e - u0s + 1);
            const uint32_t cols = (uint32_t)(u1e - u1s + 1);
            Poff[l] = off; Pu0[l] = (uint32_t)u0s; Pu1[l] = (uint32_t)u1s;
            Pcols[l] = cols; Prows[l] = rows;
            off += rows * cols;
        }
    }
    __syncthreads();

    for (uint32_t l = 0; l < 12u; ++l) {     // divergent hash staging (r9)
        const uint32_t off = Poff[l], u0s = Pu0[l], u1s = Pu1[l];
        const uint32_t cols = Pcols[l];
        const uint32_t E = Prows[l] * cols;
        const uint32_t tb = (plane * 16u + l) * TSIZE;
        for (uint32_t i = t; i < E; i += 256u) {
            const uint32_t r  = i / cols;
            const uint32_t cx = u0s + r;
            const uint32_t cy = u1s + (i - r * cols);
            sm[off + i] = tab[tb + ((cx ^ (cy * PRIME1)) & TMASK)];
        }
    }
    __syncthreads();

    const float4* __restrict__ sp = sort16 + (size_t)plane * NPTS;
    for (uint32_t i = t; i < cntB; i += 256u) {
        const float4 f = sp[start + i];
        const float c0 = f.x, c1 = f.y;
        const uint32_t orig = __float_as_uint(f.z);
        uint32_t hp[12];
#pragma unroll
        for (int l = 0; l < 12; ++l) {
            const float res = c_res[l];
            const float s0 = c0 * res;
            const float s1 = c1 * res;
            const float f0 = floorf(s0);
            const float f1 = floorf(s1);
            const float r0 = s0 - f0;        // exact f32 interp, f16 at store
            const float r1 = s1 - f1;
            const uint32_t u0 = (uint32_t)f0, u1 = (uint32_t)f1;
            const uint32_t cols = Pcols[l];
            const uint32_t ci = Poff[l] + (u0 - Pu0[l]) * cols + (u1 - Pu1[l]);
            const float2 q00 = sm[ci];
            const float2 q01 = sm[ci + 1u];
            const float2 q10 = sm[ci + cols];
            const float2 q11 = sm[ci + cols + 1u];
            const float w00 = (1.f - r0) * (1.f - r1);
            const float w01 = (1.f - r0) * r1;
            const float w10 = r0 * (1.f - r1);
            const float w11 = r0 * r1;
            hp[l] = pkh2(
                w00 * q00.x + w01 * q01.x + w10 * q10.x + w11 * q11.x,
                w00 * q00.y + w01 * q01.y + w10 * q10.y + w11 * q11.y);
        }
        const size_t d = ((size_t)orig * 3u + plane) * 3u;
        ws2u[d + 0] = make_uint4(hp[0], hp[1], hp[2],  hp[3]);
        ws2u[d + 1] = make_uint4(hp[4], hp[5], hp[6],  hp[7]);
        ws2u[d + 2] = make_uint4(hp[8], hp[9], hp[10], hp[11]);
    }
}

// ---------------- K3: levels 12-15 direct gather, XCD-pinned (r9), f16 out --
__global__ __launch_bounds__(256) void k_hi(
    const float2* __restrict__ pts2, const float2* __restrict__ tab,
    uint32_t* __restrict__ wsHh)
{
    const uint32_t b = blockIdx.x, t = threadIdx.x;
    const uint32_t xcd = b & 7u;
    const uint32_t s   = b >> 3;             // 0..767
    uint32_t g, chunk;
    if (s < 512u) { g = xcd; chunk = s; }                    // groups 0-7 full
    else { g = 8u + (xcd >> 1); chunk = ((xcd & 1u) << 8) + (s - 512u); }
    const uint32_t plane = g % 3u;
    const uint32_t lvl   = 12u + g / 3u;
    const uint32_t gabs  = plane * 16u + lvl;
    const float    res   = c_res[lvl];
    const uint32_t tb    = gabs * TSIZE;
    const float4* __restrict__ tab4 = (const float4*)tab;
    const uint32_t b4    = gabs * (TSIZE / 2u);
    const float2* __restrict__ pp = pts2 + (size_t)plane * NPTS;
    const uint32_t pt0   = chunk * 1024u + t;

    float4 P0[4], P1[4];
    float2 Q0[4], Q1[4];
    float  r0[4], r1[4];
    uint32_t sel0[4], sel1[4], oddm[4];

#pragma unroll
    for (int k = 0; k < 4; ++k) {            // issue all loads first
        const uint32_t pt = pt0 + (uint32_t)k * 256u;
        const float2 c2 = pp[pt];
        const float s0 = c2.x * res;
        const float s1 = c2.y * res;
        const float f0 = floorf(s0);
        const float f1 = floorf(s1);
        r0[k] = s0 - f0;                     // exact f32 match to reference
        r1[k] = s1 - f1;
        const uint32_t u0  = (uint32_t)f0;
        const uint32_t hy0 = (uint32_t)f1 * PRIME1;
        const uint32_t hy1 = hy0 + PRIME1;
        const uint32_t i00 = ( u0        ^ hy0) & TMASK;
        const uint32_t i01 = ( u0        ^ hy1) & TMASK;
        const uint32_t i10 = ((u0 + 1u)  ^ hy0) & TMASK;
        const uint32_t i11 = ((u0 + 1u)  ^ hy1) & TMASK;
        sel0[k] = i00 & 1u;
        sel1[k] = i01 & 1u;
        oddm[k] = u0 & 1u;
        P0[k] = tab4[b4 + (i00 >> 1)];       // covers t00 (+t10 if u0 even)
        P1[k] = tab4[b4 + (i01 >> 1)];       // covers t01 (+t11 if u0 even)
        Q0[k] = make_float2(0.f, 0.f);
        Q1[k] = make_float2(0.f, 0.f);
        if (oddm[k]) {                       // exec-masked, ~50% lanes
            Q0[k] = tab[tb + i10];
            Q1[k] = tab[tb + i11];
        }
    }
#pragma unroll
    for (int k = 0; k < 4; ++k) {
        const uint32_t pt = pt0 + (uint32_t)k * 256u;
        const float2 lo0 = make_float2(P0[k].x, P0[k].y);
        const float2 hi0 = make_float2(P0[k].z, P0[k].w);
        const float2 lo1 = make_float2(P1[k].x, P1[k].y);
        const float2 hi1 = make_float2(P1[k].z, P1[k].w);
        const float2 t00 = sel0[k] ? hi0 : lo0;
        const float2 t01 = sel1[k] ? hi1 : lo1;
        const float2 t10 = oddm[k] ? Q0[k] : (sel0[k] ? lo0 : hi0);
        const float2 t11 = oddm[k] ? Q1[k] : (sel1[k] ? lo1 : hi1);
        const float w00 = (1.f - r0[k]) * (1.f - r1[k]);
        const float w01 = (1.f - r0[k]) * r1[k];
        const float w10 = r0[k] * (1.f - r1[k]);
        const float w11 = r0[k] * r1[k];
        wsHh[(size_t)g * NPTS + pt] = pkh2(
            w00 * t00.x + w01 * t01.x + w10 * t10.x + w11 * t11.x,
            w00 * t00.y + w01 * t01.y + w10 * t10.y + w11 * t11.y);
    }
}

// ---------------- K4: combine (f16 in) -> out (f32) --------------------------
__global__ __launch_bounds__(256) void k_comb(
    const uint4* __restrict__ ws2u, const uint32_t* __restrict__ wsHh,
    float2* __restrict__ out)
{
    __shared__ uint32_t s2[2304];            // 64 pts x 36 uints (9 uint4)
    __shared__ uint32_t sh[768];             // 12 g x 64 pts
    const uint32_t b = blockIdx.x, t = threadIdx.x;
    const uint32_t pt0 = b * 64u;
    uint4* s4 = (uint4*)s2;
    for (uint32_t i = t; i < 576u; i += 256u)
        s4[i] = ws2u[(size_t)pt0 * 9u + i];
    for (uint32_t i = t; i < 768u; i += 256u) {
        const uint32_t g = i >> 6, p = i & 63u;
        sh[i] = wsHh[(size_t)g * NPTS + pt0 + p];
    }
    __syncthreads();
#pragma unroll
    for (uint32_t k = 0; k < 4u; ++k) {
        const uint32_t e = t + k * 256u;
        const uint32_t pt = e >> 4, l = e & 15u;
        float2 v;
        if (l < 12u) {
            const float2 a  = uph2(s2[pt * 36u + l]);
            const float2 bb = uph2(s2[pt * 36u + 12u + l]);
            const float2 c  = uph2(s2[pt * 36u + 24u + l]);
            v = make_float2(a.x * bb.x * c.x, a.y * bb.y * c.y);
        } else {
            const uint32_t j0 = (l - 12u) * 3u;
            const float2 a  = uph2(sh[j0 * 64u + pt]);
            const float2 bb = uph2(sh[(j0 + 1u) * 64u + pt]);
            const float2 c  = uph2(sh[(j0 + 2u) * 64u + pt]);
            v = make_float2(a.x * bb.x * c.x, a.y * bb.y * c.y);
        }
        out[(size_t)(pt0 + pt) * 16u + l] = v;
    }
}

// ---------------- Plan B fallback: r2 3-pass + transpose ---------------------
template <int P, bool FIRST>
__global__ __launch_bounds__(256) void kplane_pass(
    const float* __restrict__ pts, const float2* __restrict__ tab,
    float2* __restrict__ ws)
{
    const uint32_t b     = blockIdx.x;
    const uint32_t xcd   = b & 7u;
    const uint32_t s     = b >> 3;
    const uint32_t gi    = s >> 11;
    const uint32_t chunk = s & 2047u;
    const uint32_t lvl   = gi * 8u + xcd;
    const uint32_t pt    = chunk * 256u + threadIdx.x;
    constexpr int c0 = (P == 2) ? 1 : 0;
    constexpr int c1 = (P == 0) ? 1 : 2;
    const float a0  = pts[pt * 3u + c0];
    const float a1  = pts[pt * 3u + c1];
    const float res = c_res[lvl];
    const float s0 = a0 * res;
    const float s1 = a1 * res;
    const float f0 = floorf(s0);
    const float f1 = floorf(s1);
    const float r0 = s0 - f0;
    const float r1 = s1 - f1;
    const uint32_t u0 = (uint32_t)f0;
    const uint32_t hy0  = (uint32_t)f1 * PRIME1;
    const uint32_t hy1  = hy0 + PRIME1;
    const uint32_t base = ((uint32_t)P * 16u + lvl) * TSIZE;
    const float2 t00 = tab[base + (( u0       ^ hy0) & TMASK)];
    const float2 t01 = tab[base + (( u0       ^ hy1) & TMASK)];
    const float2 t10 = tab[base + (((u0 + 1u) ^ hy0) & TMASK)];
    const float2 t11 = tab[base + (((u0 + 1u) ^ hy1) & TMASK)];
    const float w00 = (1.f - r0) * (1.f - r1);
    const float w01 = (1.f - r0) * r1;
    const float w10 = r0 * (1.f - r1);
    const float w11 = r0 * r1;
    const float e0 = w00 * t00.x + w01 * t01.x + w10 * t10.x + w11 * t11.x;
    const float e1 = w00 * t00.y + w01 * t01.y + w10 * t10.y + w11 * t11.y;
    const uint32_t widx = lvl * NPTS + pt;
    if (FIRST) {
        ws[widx] = make_float2(e0, e1);
    } else {
        const float2 prev = ws[widx];
        ws[widx] = make_float2(prev.x * e0, prev.y * e1);
    }
}

__global__ __launch_bounds__(256) void kplane_transpose(
    const float2* __restrict__ ws, float2* __restrict__ out)
{
    const uint32_t tid = blockIdx.x * 256u + threadIdx.x;
    const uint32_t lvl = tid & 15u;
    const uint32_t pt  = tid >> 4;
    out[tid] = ws[lvl * NPTS + pt];
}

__global__ __launch_bounds__(256) void kplane_mono(
    const float* __restrict__ pts, const float2* __restrict__ tab,
    float2* __restrict__ out)
{
    const uint32_t tid = blockIdx.x * 256u + threadIdx.x;
    const uint32_t pt  = tid >> 4;
    const uint32_t lvl = tid & 15u;
    const float x = pts[pt * 3u + 0u];
    const float y = pts[pt * 3u + 1u];
    const float z = pts[pt * 3u + 2u];
    const float res = c_res[lvl];
    const float a0[3] = {x, x, y};
    const float a1[3] = {y, z, z};
    float p0 = 1.f, p1 = 1.f;
#pragma unroll
    for (int pl = 0; pl < 3; ++pl) {
        const float s0 = a0[pl] * res;
        const float s1 = a1[pl] * res;
        const float f0 = floorf(s0);
        const float f1 = floorf(s1);
        const float r0 = s0 - f0;
        const float r1 = s1 - f1;
        const uint32_t u0 = (uint32_t)f0;
        const uint32_t hy0 = (uint32_t)f1 * PRIME1;
        const uint32_t hy1 = hy0 + PRIME1;
        const uint32_t base = ((uint32_t)pl * 16u + lvl) * TSIZE;
        const float2 t00 = tab[base + (( u0       ^ hy0) & TMASK)];
        const float2 t01 = tab[base + (( u0       ^ hy1) & TMASK)];
        const float2 t10 = tab[base + (((u0 + 1u) ^ hy0) & TMASK)];
        const float2 t11 = tab[base + (((u0 + 1u) ^ hy1) & TMASK)];
        const float w00 = (1.f - r0) * (1.f - r1);
        const float w01 = (1.f - r0) * r1;
        const float w10 = r0 * (1.f - r1);
        const float w11 = r0 * r1;
        p0 *= w00 * t00.x + w01 * t01.x + w10 * t10.x + w11 * t11.x;
        p1 *= w00 * t00.y + w01 * t01.y + w10 * t10.y + w11 * t11.y;
    }
    out[pt * 16u + lvl] = make_float2(p0, p1);
}

extern "C" void kernel_launch(void* const* d_in, const int* in_sizes, int n_in,
                              void* d_out, int out_size, void* d_ws, size_t ws_size,
                              hipStream_t stream) {
    const float*  pts = (const float*)d_in[0];
    const float2* tab = (const float2*)d_in[1];
    float2*       out = (float2*)d_out;

    const size_t wsA = (size_t)NPTS * 148u;                  // 77.6 MB needed
    const size_t wsB = (size_t)16 * NPTS * sizeof(float2);   // 67.1 MB
    dim3 block256(256u);

    if (ws_size >= wsA) {
        // d_out scratch: pts2 12.6MB | sort16 25.2MB | hist | cursor
        float2*   pts2   = (float2*)d_out;
        float4*   sort16 = (float4*)(pts2 + (size_t)3 * NPTS);
        uint32_t* hist   = (uint32_t*)(sort16 + (size_t)3 * NPTS);
        uint32_t* cursor = hist + 768;
        // d_ws: ws2u (NPTS x 9 uint4, 75.5MB) | wsHh (12 x NPTS uint, 25.2MB)
        uint4*    ws2u   = (uint4*)d_ws;
        uint32_t* wsHh   = (uint32_t*)(ws2u + (size_t)NPTS * 9u);

        hipMemsetAsync(hist, 0, 1536u * sizeof(uint32_t), stream);
        hipLaunchKernelGGL(k_packhist, dim3(2048u), block256, 0, stream,
                           pts, pts2, hist);
        hipLaunchKernelGGL(k_scatter,  dim3(192u),  block256, 0, stream,
                           pts2, hist, cursor, sort16);
        hipLaunchKernelGGL(k_low,      dim3(768u),  block256, 0, stream,
                           tab, sort16, hist, ws2u);
        hipLaunchKernelGGL(k_hi,       dim3(6144u), block256, 0, stream,
                           pts2, tab, wsHh);
        hipLaunchKernelGGL(k_comb,     dim3(NPTS / 64u), block256, 0, stream,
                           ws2u, wsHh, out);
    } else if (ws_size >= wsB) {
        float2* ws = (float2*)d_ws;
        dim3 grid(16u * (NPTS / 256u));
        hipLaunchKernelGGL((kplane_pass<0, true >), grid, block256, 0, stream, pts, tab, ws);
        hipLaunchKernelGGL((kplane_pass<1, false>), grid, block256, 0, stream, pts, tab, ws);
        hipLaunchKernelGGL((kplane_pass<2, false>), grid, block256, 0, stream, pts, tab, ws);
        dim3 tgrid((NPTS * 16u) / 256u);
        hipLaunchKernelGGL(kplane_transpose, tgrid, block256, 0, stream, ws, out);
    } else {
        dim3 grid((NPTS * 16u) / 256u);
        hipLaunchKernelGGL(kplane_mono, grid, block256, 0, stream, pts, tab, out);
    }
}